// Round 1
// baseline (3365.694 us; speedup 1.0000x reference)
//
#include <hip/hip_runtime.h>
#include <hip/hip_bf16.h>

// Problem constants (fixed by the reference)
constexpr int N_ = 2000;   // nodes
constexpr int E_ = 4096;   // edges
constexpr int H_ = 256;    // hidden
constexpr int KH_ = 128;   // he dim (mlp1 out)
constexpr int NV_ = H_ * KH_; // 32768, V row length (layout [o*128+k])

__device__ __forceinline__ float bf_lo(unsigned u) { return __uint_as_float(u << 16); }
__device__ __forceinline__ float bf_hi(unsigned u) { return __uint_as_float(u & 0xffff0000u); }

// out = relu([emb[x], pos] @ lin0_W.T + b)   grid N, block 256
__global__ void k_lin0(const int* __restrict__ x, const float* __restrict__ pos,
                       const float* __restrict__ emb, const float* __restrict__ W,
                       const float* __restrict__ b, float* __restrict__ out) {
    int n = blockIdx.x, t = threadIdx.x;
    __shared__ float in_p[8];
    if (t < 5) in_p[t] = emb[x[n] * 5 + t];
    else if (t < 8) in_p[t] = pos[n * 3 + (t - 5)];
    __syncthreads();
    float acc = b[t];
#pragma unroll
    for (int i = 0; i < 8; i++) acc += in_p[i] * W[t * 8 + i];
    out[n * H_ + t] = fmaxf(acc, 0.f);
}

// he = relu(edge_atr @ mlp1_W.T + b)   grid E, block 128
__global__ void k_he(const float* __restrict__ ea, const float* __restrict__ W,
                     const float* __restrict__ b, float* __restrict__ he) {
    int e = blockIdx.x, t = threadIdx.x;
    __shared__ float a[5];
    if (t < 5) a[t] = ea[e * 5 + t];
    __syncthreads();
    float acc = b[t];
#pragma unroll
    for (int i = 0; i < 5; i++) acc += a[i] * W[t * 5 + i];
    he[e * KH_ + t] = fmaxf(acc, 0.f);
}

__global__ void k_counts(const int* __restrict__ ei, float* __restrict__ counts) {
    int e = blockIdx.x * blockDim.x + threadIdx.x;
    if (e < E_) atomicAdd(&counts[ei[E_ + e]], 1.0f);
}

// outb[n,o] = sum_h out[n,h] * mlp2_b[h*256+o]   grid N, block 256
__global__ void k_outb(const float* __restrict__ hbuf, const float* __restrict__ b2,
                       float* __restrict__ outb) {
    int n = blockIdx.x, o = threadIdx.x;
    __shared__ float hr[H_];
    hr[o] = hbuf[n * H_ + o];
    __syncthreads();
    float acc = 0.f;
    for (int h = 0; h < H_; h++) acc += hr[h] * b2[h * H_ + o];
    outb[n * H_ + o] = acc;
}

// V = out(2000x256) @ mlp2_W-as-(256x32768), output bf16.
// 64x64 tile, 256 threads, 4x4 microtile, K-tile 16.
__global__ __launch_bounds__(256) void k_gemm_V(const float* __restrict__ A,
                                                const float* __restrict__ B,
                                                __hip_bfloat16* __restrict__ C, int M) {
    __shared__ float As[64][17];
    __shared__ float Bs[16][64];
    const int K = H_, NN = NV_;
    int t = threadIdx.x;
    int tx = t & 15, ty = t >> 4;
    int row0 = blockIdx.y * 64, col0 = blockIdx.x * 64;
    float acc[4][4] = {};
    for (int k0 = 0; k0 < K; k0 += 16) {
#pragma unroll
        for (int i = 0; i < 4; i++) {
            int e = t + i * 256;
            int m = e >> 4, kk = e & 15;
            int gm = row0 + m;
            As[m][kk] = (gm < M) ? A[gm * K + k0 + kk] : 0.f;
        }
#pragma unroll
        for (int i = 0; i < 4; i++) {
            int e = t + i * 256;
            int n = e & 63, kk = e >> 6;
            Bs[kk][n] = B[(size_t)(k0 + kk) * NN + col0 + n];
        }
        __syncthreads();
#pragma unroll
        for (int kk = 0; kk < 16; kk++) {
            float a0 = As[ty * 4 + 0][kk];
            float a1 = As[ty * 4 + 1][kk];
            float a2 = As[ty * 4 + 2][kk];
            float a3 = As[ty * 4 + 3][kk];
            float4 bv = *reinterpret_cast<const float4*>(&Bs[kk][tx * 4]);
            acc[0][0] += a0 * bv.x; acc[0][1] += a0 * bv.y; acc[0][2] += a0 * bv.z; acc[0][3] += a0 * bv.w;
            acc[1][0] += a1 * bv.x; acc[1][1] += a1 * bv.y; acc[1][2] += a1 * bv.z; acc[1][3] += a1 * bv.w;
            acc[2][0] += a2 * bv.x; acc[2][1] += a2 * bv.y; acc[2][2] += a2 * bv.z; acc[2][3] += a2 * bv.w;
            acc[3][0] += a3 * bv.x; acc[3][1] += a3 * bv.y; acc[3][2] += a3 * bv.z; acc[3][3] += a3 * bv.w;
        }
        __syncthreads();
    }
#pragma unroll
    for (int i = 0; i < 4; i++) {
        int gm = row0 + ty * 4 + i;
        if (gm < M) {
            size_t base = (size_t)gm * NN + col0 + tx * 4;
#pragma unroll
            for (int j = 0; j < 4; j++) C[base + j] = __float2bfloat16(acc[i][j]);
        }
    }
}

// msg[e,o] = he[e,:].V[row[e],o,:] + outb[row[e],o]; atomicAdd into agg[col[e],o]
// grid E, block 256
__global__ void k_msg(const int* __restrict__ ei, const float* __restrict__ he,
                      const __hip_bfloat16* __restrict__ V, const float* __restrict__ outb,
                      float* __restrict__ agg) {
    int e = blockIdx.x, o = threadIdx.x;
    __shared__ float hs[KH_];
    if (o < KH_) hs[o] = he[e * KH_ + o];
    __syncthreads();
    int r = ei[e], c = ei[E_ + e];
    float acc = outb[(size_t)r * H_ + o];
    const uint4* vp4 = reinterpret_cast<const uint4*>(V + (size_t)r * NV_ + (size_t)o * KH_);
#pragma unroll
    for (int q = 0; q < KH_ / 8; q++) {
        uint4 u = vp4[q];
        const float* hp = hs + q * 8;
        acc += hp[0] * bf_lo(u.x) + hp[1] * bf_hi(u.x)
             + hp[2] * bf_lo(u.y) + hp[3] * bf_hi(u.y)
             + hp[4] * bf_lo(u.z) + hp[5] * bf_hi(u.z)
             + hp[6] * bf_lo(u.w) + hp[7] * bf_hi(u.w);
    }
    atomicAdd(&agg[(size_t)c * H_ + o], acc);
}

// m = relu(agg / max(counts,1) + conv_b), in place on agg
__global__ void k_m(float* __restrict__ aggm, const float* __restrict__ counts,
                    const float* __restrict__ conv_b) {
    int i = blockIdx.x * blockDim.x + threadIdx.x;
    if (i >= N_ * H_) return;
    int n = i >> 8, o = i & 255;
    float c = fmaxf(counts[n], 1.0f);
    aggm[i] = fmaxf(aggm[i] / c + conv_b[o], 0.f);
}

// gi = m @ Wih.T + bih ; gh = h @ Whh.T + bhh   grid (N,3), block 256
__global__ void k_gru_gemm(const float* __restrict__ m, const float* __restrict__ h,
                           const float* __restrict__ Wih, const float* __restrict__ Whh,
                           const float* __restrict__ bih, const float* __restrict__ bhh,
                           float* __restrict__ gi, float* __restrict__ gh) {
    int n = blockIdx.x, g = blockIdx.y, t = threadIdx.x;
    int j = g * H_ + t;
    __shared__ float ms[H_], hs2[H_];
    ms[t] = m[n * H_ + t];
    hs2[t] = h[n * H_ + t];
    __syncthreads();
    const float4* wi = reinterpret_cast<const float4*>(Wih + (size_t)j * H_);
    const float4* wh = reinterpret_cast<const float4*>(Whh + (size_t)j * H_);
    float ai = bih[j], ah = bhh[j];
#pragma unroll 4
    for (int k4 = 0; k4 < H_ / 4; k4++) {
        float4 a = wi[k4], b = wh[k4];
        ai += ms[k4 * 4 + 0] * a.x + ms[k4 * 4 + 1] * a.y + ms[k4 * 4 + 2] * a.z + ms[k4 * 4 + 3] * a.w;
        ah += hs2[k4 * 4 + 0] * b.x + hs2[k4 * 4 + 1] * b.y + hs2[k4 * 4 + 2] * b.z + hs2[k4 * 4 + 3] * b.w;
    }
    gi[(size_t)n * 768 + j] = ai;
    gh[(size_t)n * 768 + j] = ah;
}

__global__ void k_gru_update(const float* __restrict__ gi, const float* __restrict__ gh,
                             float* __restrict__ h) {
    int i = blockIdx.x * blockDim.x + threadIdx.x;
    if (i >= N_ * H_) return;
    int n = i >> 8, j = i & 255;
    const float* gip = gi + (size_t)n * 768;
    const float* ghp = gh + (size_t)n * 768;
    float r = 1.f / (1.f + expf(-(gip[j] + ghp[j])));
    float z = 1.f / (1.f + expf(-(gip[H_ + j] + ghp[H_ + j])));
    float nn = tanhf(gip[2 * H_ + j] + r * ghp[2 * H_ + j]);
    h[i] = (1.f - z) * nn + z * h[i];
}

// o1 = relu([h[row],h[col]] @ lin1_W.T + b)   grid E, block 256
__global__ void k_o1(const int* __restrict__ ei, const float* __restrict__ h,
                     const float* __restrict__ W, const float* __restrict__ b,
                     float* __restrict__ o1) {
    int e = blockIdx.x, t = threadIdx.x;
    __shared__ float oc[2 * H_];
    int r = ei[e], c = ei[E_ + e];
    oc[t] = h[(size_t)r * H_ + t];
    oc[H_ + t] = h[(size_t)c * H_ + t];
    __syncthreads();
    const float4* w4 = reinterpret_cast<const float4*>(W + (size_t)t * 2 * H_);
    float acc = b[t];
#pragma unroll 4
    for (int k4 = 0; k4 < 2 * H_ / 4; k4++) {
        float4 a = w4[k4];
        acc += oc[k4 * 4 + 0] * a.x + oc[k4 * 4 + 1] * a.y + oc[k4 * 4 + 2] * a.z + oc[k4 * 4 + 3] * a.w;
    }
    o1[(size_t)e * H_ + t] = fmaxf(acc, 0.f);
}

// out2 = o1 @ lin2_W.T + b (242 cols) -> d_out[0 .. E*242)   grid E, block 256
__global__ void k_out2(const float* __restrict__ o1, const float* __restrict__ W,
                       const float* __restrict__ b, float* __restrict__ out) {
    int e = blockIdx.x, t = threadIdx.x;
    __shared__ float os[H_];
    os[t] = o1[(size_t)e * H_ + t];
    __syncthreads();
    if (t < 242) {
        const float4* w4 = reinterpret_cast<const float4*>(W + (size_t)t * H_);
        float acc = b[t];
#pragma unroll 4
        for (int k4 = 0; k4 < H_ / 4; k4++) {
            float4 a = w4[k4];
            acc += os[k4 * 4 + 0] * a.x + os[k4 * 4 + 1] * a.y + os[k4 * 4 + 2] * a.z + os[k4 * 4 + 3] * a.w;
        }
        out[(size_t)e * 242 + t] = acc;
    }
}

// h1 = [h[row],h[col]] @ l6_W1.T + b (128 cols)   grid E, block 128
__global__ void k_h1(const int* __restrict__ ei, const float* __restrict__ h,
                     const float* __restrict__ W, const float* __restrict__ b,
                     float* __restrict__ h1) {
    int e = blockIdx.x, t = threadIdx.x;
    __shared__ float oc[2 * H_];
    int r = ei[e], c = ei[E_ + e];
    oc[t] = h[(size_t)r * H_ + t];
    oc[t + 128] = h[(size_t)r * H_ + t + 128];
    oc[H_ + t] = h[(size_t)c * H_ + t];
    oc[H_ + t + 128] = h[(size_t)c * H_ + t + 128];
    __syncthreads();
    const float4* w4 = reinterpret_cast<const float4*>(W + (size_t)t * 2 * H_);
    float acc = b[t];
#pragma unroll 4
    for (int k4 = 0; k4 < 2 * H_ / 4; k4++) {
        float4 a = w4[k4];
        acc += oc[k4 * 4 + 0] * a.x + oc[k4 * 4 + 1] * a.y + oc[k4 * 4 + 2] * a.z + oc[k4 * 4 + 3] * a.w;
    }
    h1[(size_t)e * 128 + t] = acc;
}

// batchnorm stats over E rows, per column j   grid 128, block 256
__global__ void k_bnstats(const float* __restrict__ h1, float* __restrict__ mu,
                          float* __restrict__ rsig) {
    int j = blockIdx.x, t = threadIdx.x;
    float s = 0.f, ss = 0.f;
    for (int e = t; e < E_; e += 256) {
        float v = h1[(size_t)e * 128 + j];
        s += v;
        ss += v * v;
    }
    __shared__ float rs[256], rss[256];
    rs[t] = s; rss[t] = ss;
    __syncthreads();
    for (int off = 128; off > 0; off >>= 1) {
        if (t < off) { rs[t] += rs[t + off]; rss[t] += rss[t + off]; }
        __syncthreads();
    }
    if (t == 0) {
        float m_ = rs[0] / E_;
        float v_ = rss[0] / E_ - m_ * m_;
        mu[j] = m_;
        rsig[j] = rsqrtf(v_ + 1e-5f);
    }
}

// precs[e] = relu(bn(h1[e])) . l6_W2 + b -> d_out[E*242 + e]
__global__ void k_precs(const float* __restrict__ h1, const float* __restrict__ mu,
                        const float* __restrict__ rsig, const float* __restrict__ g,
                        const float* __restrict__ bb, const float* __restrict__ W2,
                        const float* __restrict__ b2, float* __restrict__ out) {
    int e = blockIdx.x * blockDim.x + threadIdx.x;
    if (e >= E_) return;
    float acc = b2[0];
#pragma unroll 4
    for (int j = 0; j < 128; j++) {
        float v = (h1[(size_t)e * 128 + j] - mu[j]) * rsig[j] * g[j] + bb[j];
        acc += fmaxf(v, 0.f) * W2[j];
    }
    out[(size_t)E_ * 242 + e] = acc;
}

extern "C" void kernel_launch(void* const* d_in, const int* in_sizes, int n_in,
                              void* d_out, int out_size, void* d_ws, size_t ws_size,
                              hipStream_t stream) {
    const int*   x        = (const int*)  d_in[0];
    const float* pos      = (const float*)d_in[1];
    const int*   ei       = (const int*)  d_in[2];
    const float* edge_atr = (const float*)d_in[3];
    const float* emb      = (const float*)d_in[4];
    const float* lin0_W   = (const float*)d_in[5];
    const float* lin0_b   = (const float*)d_in[6];
    const float* mlp1_W   = (const float*)d_in[7];
    const float* mlp1_b   = (const float*)d_in[8];
    const float* mlp2_W   = (const float*)d_in[9];
    const float* mlp2_b   = (const float*)d_in[10];
    const float* conv_b   = (const float*)d_in[11];
    const float* gru_Wih  = (const float*)d_in[12];
    const float* gru_Whh  = (const float*)d_in[13];
    const float* gru_bih  = (const float*)d_in[14];
    const float* gru_bhh  = (const float*)d_in[15];
    const float* lin1_W   = (const float*)d_in[16];
    const float* lin1_b   = (const float*)d_in[17];
    const float* lin2_W   = (const float*)d_in[18];
    const float* lin2_b   = (const float*)d_in[19];
    const float* l6_W1    = (const float*)d_in[20];
    const float* l6_b1    = (const float*)d_in[21];
    const float* bn_g     = (const float*)d_in[22];
    const float* bn_b     = (const float*)d_in[23];
    const float* l6_W2    = (const float*)d_in[24];
    const float* l6_b2    = (const float*)d_in[25];
    float* out = (float*)d_out;

    // workspace layout
    char* w = (char*)d_ws;
    size_t off = 0;
    auto alloc = [&](size_t bytes) -> void* {
        void* p = w + off;
        off = (off + bytes + 255) & ~(size_t)255;
        return p;
    };
    float* hbuf   = (float*)alloc((size_t)N_ * H_ * 4);
    float* aggm   = (float*)alloc((size_t)N_ * H_ * 4);   // agg, then m in place
    float* outb   = (float*)alloc((size_t)N_ * H_ * 4);
    float* he     = (float*)alloc((size_t)E_ * KH_ * 4);
    float* gi     = (float*)alloc((size_t)N_ * 768 * 4);
    float* gh     = (float*)alloc((size_t)N_ * 768 * 4);
    float* o1     = (float*)alloc((size_t)E_ * H_ * 4);
    float* h1     = (float*)alloc((size_t)E_ * 128 * 4);
    float* counts = (float*)alloc((size_t)N_ * 4);
    float* mu     = (float*)alloc(128 * 4);
    float* rsig   = (float*)alloc(128 * 4);
    __hip_bfloat16* V = (__hip_bfloat16*)alloc((size_t)N_ * NV_ * 2);  // 131 MB

    k_lin0<<<N_, 256, 0, stream>>>(x, pos, emb, lin0_W, lin0_b, hbuf);
    k_he<<<E_, 128, 0, stream>>>(edge_atr, mlp1_W, mlp1_b, he);
    hipMemsetAsync(counts, 0, (size_t)N_ * 4, stream);
    k_counts<<<(E_ + 255) / 256, 256, 0, stream>>>(ei, counts);

    for (int it = 0; it < 3; it++) {
        k_outb<<<N_, 256, 0, stream>>>(hbuf, mlp2_b, outb);
        dim3 gv(NV_ / 64, (N_ + 63) / 64);
        k_gemm_V<<<gv, 256, 0, stream>>>(hbuf, mlp2_W, V, N_);
        hipMemsetAsync(aggm, 0, (size_t)N_ * H_ * 4, stream);
        k_msg<<<E_, 256, 0, stream>>>(ei, he, V, outb, aggm);
        k_m<<<(N_ * H_ + 255) / 256, 256, 0, stream>>>(aggm, counts, conv_b);
        k_gru_gemm<<<dim3(N_, 3), 256, 0, stream>>>(aggm, hbuf, gru_Wih, gru_Whh,
                                                    gru_bih, gru_bhh, gi, gh);
        k_gru_update<<<(N_ * H_ + 255) / 256, 256, 0, stream>>>(gi, gh, hbuf);
    }

    k_o1<<<E_, 256, 0, stream>>>(ei, hbuf, lin1_W, lin1_b, o1);
    k_out2<<<E_, 256, 0, stream>>>(o1, lin2_W, lin2_b, out);
    k_h1<<<E_, 128, 0, stream>>>(ei, hbuf, l6_W1, l6_b1, h1);
    k_bnstats<<<128, 256, 0, stream>>>(h1, mu, rsig);
    k_precs<<<(E_ + 255) / 256, 256, 0, stream>>>(h1, mu, rsig, bn_g, bn_b, l6_W2, l6_b2, out);
}

// Round 2
// 2025.721 us; speedup vs baseline: 1.6615x; 1.6615x over previous
//
#include <hip/hip_runtime.h>
#include <hip/hip_bf16.h>

// Problem constants (fixed by the reference)
constexpr int N_ = 2000;   // nodes
constexpr int E_ = 4096;   // edges
constexpr int H_ = 256;    // hidden
constexpr int KH_ = 128;   // he dim (mlp1 out)
constexpr int NV_ = H_ * KH_; // 32768, V row length (layout [o*128+k])
constexpr int MPAD_ = 2048;   // padded M for the MFMA GEMM

typedef short bf16x8 __attribute__((ext_vector_type(8)));
typedef float f32x4  __attribute__((ext_vector_type(4)));

__device__ __forceinline__ float bf_lo(unsigned u) { return __uint_as_float(u << 16); }
__device__ __forceinline__ float bf_hi(unsigned u) { return __uint_as_float(u & 0xffff0000u); }

// out = relu([emb[x], pos] @ lin0_W.T + b)   grid N, block 256
__global__ void k_lin0(const int* __restrict__ x, const float* __restrict__ pos,
                       const float* __restrict__ emb, const float* __restrict__ W,
                       const float* __restrict__ b, float* __restrict__ out) {
    int n = blockIdx.x, t = threadIdx.x;
    __shared__ float in_p[8];
    if (t < 5) in_p[t] = emb[x[n] * 5 + t];
    else if (t < 8) in_p[t] = pos[n * 3 + (t - 5)];
    __syncthreads();
    float acc = b[t];
#pragma unroll
    for (int i = 0; i < 8; i++) acc += in_p[i] * W[t * 8 + i];
    out[n * H_ + t] = fmaxf(acc, 0.f);
}

// he = relu(edge_atr @ mlp1_W.T + b)   grid E, block 128
__global__ void k_he(const float* __restrict__ ea, const float* __restrict__ W,
                     const float* __restrict__ b, float* __restrict__ he) {
    int e = blockIdx.x, t = threadIdx.x;
    __shared__ float a[5];
    if (t < 5) a[t] = ea[e * 5 + t];
    __syncthreads();
    float acc = b[t];
#pragma unroll
    for (int i = 0; i < 5; i++) acc += a[i] * W[t * 5 + i];
    he[e * KH_ + t] = fmaxf(acc, 0.f);
}

__global__ void k_counts(const int* __restrict__ ei, float* __restrict__ counts) {
    int e = blockIdx.x * blockDim.x + threadIdx.x;
    if (e < E_) atomicAdd(&counts[ei[E_ + e]], 1.0f);
}

// outb[n,o] = sum_h out[n,h] * mlp2_b[h*256+o]   grid N, block 256
__global__ void k_outb(const float* __restrict__ hbuf, const float* __restrict__ b2,
                       float* __restrict__ outb) {
    int n = blockIdx.x, o = threadIdx.x;
    __shared__ float hr[H_];
    hr[o] = hbuf[n * H_ + o];
    __syncthreads();
    float acc = 0.f;
    for (int h = 0; h < H_; h++) acc += hr[h] * b2[h * H_ + o];
    outb[n * H_ + o] = acc;
}

// Bt[n][k] = mlp2_W[k*32768 + n] as bf16 (transpose+convert), once per launch.
// grid (512, 8), block 256; tile 32k x 64n via LDS.
__global__ void k_trans_bt(const float* __restrict__ W, __hip_bfloat16* __restrict__ Bt) {
    __shared__ float tile[32][65];
    int t = threadIdx.x;
    int n0 = blockIdx.x * 64, k0 = blockIdx.y * 32;
#pragma unroll
    for (int i = 0; i < 8; i++) {
        int idx = t + i * 256;
        int kk = idx >> 6, nn = idx & 63;
        tile[kk][nn] = W[(size_t)(k0 + kk) * NV_ + n0 + nn];
    }
    __syncthreads();
#pragma unroll
    for (int i = 0; i < 8; i++) {
        int idx = t + i * 256;
        int nn = idx >> 5, kk = idx & 31;
        Bt[(size_t)(n0 + nn) * H_ + k0 + kk] = __float2bfloat16(tile[kk][nn]);
    }
}

// Abf[n][k] = bf16(hbuf[n][k]) for n<2000, 0 for pad rows.  grid 2048, block 256
__global__ void k_abf(const float* __restrict__ hbuf, __hip_bfloat16* __restrict__ Abf) {
    int i = blockIdx.x * 256 + threadIdx.x;   // one elem per thread, 2048*256 total
    int n = i >> 8;
    Abf[i] = (n < N_) ? __float2bfloat16(hbuf[i]) : __float2bfloat16(0.f);
}

// V = Abf(2048x256 bf16) @ Bt^T(32768x256 bf16, n-major) -> bf16, MFMA 16x16x32.
// 128x128 block tile, 4 waves (2x2), each wave 4x4 of 16x16 tiles. BK=32.
// Staging via global_load_lds width=16 (dest = wave-uniform base + lane*16).
__global__ __launch_bounds__(256) void k_gemm_V_mfma(const __hip_bfloat16* __restrict__ A,
                                                     const __hip_bfloat16* __restrict__ Bt,
                                                     __hip_bfloat16* __restrict__ C) {
    __shared__ short As[128 * 32];   // [row][k] row-major, 8 KB
    __shared__ short Bs[128 * 32];   // [ncol][k] row-major, 8 KB
    int t = threadIdx.x;
    int lane = t & 63, wave = t >> 6;
    int wm = wave >> 1, wn = wave & 1;
    int quad = lane >> 4, l16 = lane & 15;
    int row0 = blockIdx.y * 128, col0 = blockIdx.x * 128;

    f32x4 acc[4][4] = {};

    int r_ld = (lane >> 2);            // 0..15 row within chunk
    int koff = (lane & 3) * 8;         // 0,8,16,24

    for (int k0 = 0; k0 < H_; k0 += 32) {
#pragma unroll
        for (int c = 0; c < 4; c++) {
            int q = wave * 4 + c;       // 0..15; <8 = A chunks, >=8 = B chunks
            int ch = q & 7;
            int r = ch * 16 + r_ld;
            const __hip_bfloat16* gp;
            short* lp;
            if (q < 8) { gp = A  + ((size_t)(row0 + r) << 8) + k0 + koff; lp = As + ch * 512; }
            else       { gp = Bt + ((size_t)(col0 + r) << 8) + k0 + koff; lp = Bs + ch * 512; }
            __builtin_amdgcn_global_load_lds(
                (const __attribute__((address_space(1))) unsigned int*)(uintptr_t)gp,
                (__attribute__((address_space(3))) unsigned int*)(uintptr_t)lp,
                16, 0, 0);
        }
        __syncthreads();   // drains vmcnt (global_load_lds) + barrier
        bf16x8 a[4], b[4];
#pragma unroll
        for (int i = 0; i < 4; i++)
            a[i] = *(const bf16x8*)&As[(wm * 64 + i * 16 + l16) * 32 + quad * 8];
#pragma unroll
        for (int j = 0; j < 4; j++)
            b[j] = *(const bf16x8*)&Bs[(wn * 64 + j * 16 + l16) * 32 + quad * 8];
#pragma unroll
        for (int i = 0; i < 4; i++)
#pragma unroll
            for (int j = 0; j < 4; j++)
                acc[i][j] = __builtin_amdgcn_mfma_f32_16x16x32_bf16(a[i], b[j], acc[i][j], 0, 0, 0);
        __syncthreads();
    }

    // epilogue: C/D layout col=lane&15, row=quad*4+reg
#pragma unroll
    for (int i = 0; i < 4; i++) {
        int gm0 = row0 + wm * 64 + i * 16 + quad * 4;
#pragma unroll
        for (int r = 0; r < 4; r++) {
            int gm = gm0 + r;
            if (gm < N_) {
                size_t base = (size_t)gm * NV_ + col0 + wn * 64 + l16;
#pragma unroll
                for (int j = 0; j < 4; j++)
                    C[base + j * 16] = __float2bfloat16(acc[i][j][r]);
            }
        }
    }
}

// msg[e,o] = he[e,:].V[row[e],o,:] + outb[row[e],o]; atomicAdd into agg[col[e],o]
// grid E, block 256
__global__ void k_msg(const int* __restrict__ ei, const float* __restrict__ he,
                      const __hip_bfloat16* __restrict__ V, const float* __restrict__ outb,
                      float* __restrict__ agg) {
    int e = blockIdx.x, o = threadIdx.x;
    __shared__ float hs[KH_];
    if (o < KH_) hs[o] = he[e * KH_ + o];
    __syncthreads();
    int r = ei[e], c = ei[E_ + e];
    float acc = outb[(size_t)r * H_ + o];
    const uint4* vp4 = reinterpret_cast<const uint4*>(V + (size_t)r * NV_ + (size_t)o * KH_);
#pragma unroll
    for (int q = 0; q < KH_ / 8; q++) {
        uint4 u = vp4[q];
        const float* hp = hs + q * 8;
        acc += hp[0] * bf_lo(u.x) + hp[1] * bf_hi(u.x)
             + hp[2] * bf_lo(u.y) + hp[3] * bf_hi(u.y)
             + hp[4] * bf_lo(u.z) + hp[5] * bf_hi(u.z)
             + hp[6] * bf_lo(u.w) + hp[7] * bf_hi(u.w);
    }
    atomicAdd(&agg[(size_t)c * H_ + o], acc);
}

// m = relu(agg / max(counts,1) + conv_b), in place on agg
__global__ void k_m(float* __restrict__ aggm, const float* __restrict__ counts,
                    const float* __restrict__ conv_b) {
    int i = blockIdx.x * blockDim.x + threadIdx.x;
    if (i >= N_ * H_) return;
    int n = i >> 8, o = i & 255;
    float c = fmaxf(counts[n], 1.0f);
    aggm[i] = fmaxf(aggm[i] / c + conv_b[o], 0.f);
}

// gi = m @ Wih.T + bih ; gh = h @ Whh.T + bhh   grid (N,3), block 256
__global__ void k_gru_gemm(const float* __restrict__ m, const float* __restrict__ h,
                           const float* __restrict__ Wih, const float* __restrict__ Whh,
                           const float* __restrict__ bih, const float* __restrict__ bhh,
                           float* __restrict__ gi, float* __restrict__ gh) {
    int n = blockIdx.x, g = blockIdx.y, t = threadIdx.x;
    int j = g * H_ + t;
    __shared__ float ms[H_], hs2[H_];
    ms[t] = m[n * H_ + t];
    hs2[t] = h[n * H_ + t];
    __syncthreads();
    const float4* wi = reinterpret_cast<const float4*>(Wih + (size_t)j * H_);
    const float4* wh = reinterpret_cast<const float4*>(Whh + (size_t)j * H_);
    float ai = bih[j], ah = bhh[j];
#pragma unroll 4
    for (int k4 = 0; k4 < H_ / 4; k4++) {
        float4 a = wi[k4], b = wh[k4];
        ai += ms[k4 * 4 + 0] * a.x + ms[k4 * 4 + 1] * a.y + ms[k4 * 4 + 2] * a.z + ms[k4 * 4 + 3] * a.w;
        ah += hs2[k4 * 4 + 0] * b.x + hs2[k4 * 4 + 1] * b.y + hs2[k4 * 4 + 2] * b.z + hs2[k4 * 4 + 3] * b.w;
    }
    gi[(size_t)n * 768 + j] = ai;
    gh[(size_t)n * 768 + j] = ah;
}

__global__ void k_gru_update(const float* __restrict__ gi, const float* __restrict__ gh,
                             float* __restrict__ h) {
    int i = blockIdx.x * blockDim.x + threadIdx.x;
    if (i >= N_ * H_) return;
    int n = i >> 8, j = i & 255;
    const float* gip = gi + (size_t)n * 768;
    const float* ghp = gh + (size_t)n * 768;
    float r = 1.f / (1.f + expf(-(gip[j] + ghp[j])));
    float z = 1.f / (1.f + expf(-(gip[H_ + j] + ghp[H_ + j])));
    float nn = tanhf(gip[2 * H_ + j] + r * ghp[2 * H_ + j]);
    h[i] = (1.f - z) * nn + z * h[i];
}

// o1 = relu([h[row],h[col]] @ lin1_W.T + b)   grid E, block 256
__global__ void k_o1(const int* __restrict__ ei, const float* __restrict__ h,
                     const float* __restrict__ W, const float* __restrict__ b,
                     float* __restrict__ o1) {
    int e = blockIdx.x, t = threadIdx.x;
    __shared__ float oc[2 * H_];
    int r = ei[e], c = ei[E_ + e];
    oc[t] = h[(size_t)r * H_ + t];
    oc[H_ + t] = h[(size_t)c * H_ + t];
    __syncthreads();
    const float4* w4 = reinterpret_cast<const float4*>(W + (size_t)t * 2 * H_);
    float acc = b[t];
#pragma unroll 4
    for (int k4 = 0; k4 < 2 * H_ / 4; k4++) {
        float4 a = w4[k4];
        acc += oc[k4 * 4 + 0] * a.x + oc[k4 * 4 + 1] * a.y + oc[k4 * 4 + 2] * a.z + oc[k4 * 4 + 3] * a.w;
    }
    o1[(size_t)e * H_ + t] = fmaxf(acc, 0.f);
}

// out2 = o1 @ lin2_W.T + b (242 cols) -> d_out[0 .. E*242)   grid E, block 256
__global__ void k_out2(const float* __restrict__ o1, const float* __restrict__ W,
                       const float* __restrict__ b, float* __restrict__ out) {
    int e = blockIdx.x, t = threadIdx.x;
    __shared__ float os[H_];
    os[t] = o1[(size_t)e * H_ + t];
    __syncthreads();
    if (t < 242) {
        const float4* w4 = reinterpret_cast<const float4*>(W + (size_t)t * H_);
        float acc = b[t];
#pragma unroll 4
        for (int k4 = 0; k4 < H_ / 4; k4++) {
            float4 a = w4[k4];
            acc += os[k4 * 4 + 0] * a.x + os[k4 * 4 + 1] * a.y + os[k4 * 4 + 2] * a.z + os[k4 * 4 + 3] * a.w;
        }
        out[(size_t)e * 242 + t] = acc;
    }
}

// h1 = [h[row],h[col]] @ l6_W1.T + b (128 cols)   grid E, block 128
__global__ void k_h1(const int* __restrict__ ei, const float* __restrict__ h,
                     const float* __restrict__ W, const float* __restrict__ b,
                     float* __restrict__ h1) {
    int e = blockIdx.x, t = threadIdx.x;
    __shared__ float oc[2 * H_];
    int r = ei[e], c = ei[E_ + e];
    oc[t] = h[(size_t)r * H_ + t];
    oc[t + 128] = h[(size_t)r * H_ + t + 128];
    oc[H_ + t] = h[(size_t)c * H_ + t];
    oc[H_ + t + 128] = h[(size_t)c * H_ + t + 128];
    __syncthreads();
    const float4* w4 = reinterpret_cast<const float4*>(W + (size_t)t * 2 * H_);
    float acc = b[t];
#pragma unroll 4
    for (int k4 = 0; k4 < 2 * H_ / 4; k4++) {
        float4 a = w4[k4];
        acc += oc[k4 * 4 + 0] * a.x + oc[k4 * 4 + 1] * a.y + oc[k4 * 4 + 2] * a.z + oc[k4 * 4 + 3] * a.w;
    }
    h1[(size_t)e * 128 + t] = acc;
}

// batchnorm stats over E rows, per column j   grid 128, block 256
__global__ void k_bnstats(const float* __restrict__ h1, float* __restrict__ mu,
                          float* __restrict__ rsig) {
    int j = blockIdx.x, t = threadIdx.x;
    float s = 0.f, ss = 0.f;
    for (int e = t; e < E_; e += 256) {
        float v = h1[(size_t)e * 128 + j];
        s += v;
        ss += v * v;
    }
    __shared__ float rs[256], rss[256];
    rs[t] = s; rss[t] = ss;
    __syncthreads();
    for (int off = 128; off > 0; off >>= 1) {
        if (t < off) { rs[t] += rs[t + off]; rss[t] += rss[t + off]; }
        __syncthreads();
    }
    if (t == 0) {
        float m_ = rs[0] / E_;
        float v_ = rss[0] / E_ - m_ * m_;
        mu[j] = m_;
        rsig[j] = rsqrtf(v_ + 1e-5f);
    }
}

// precs[e] = relu(bn(h1[e])) . l6_W2 + b -> d_out[E*242 + e]
__global__ void k_precs(const float* __restrict__ h1, const float* __restrict__ mu,
                        const float* __restrict__ rsig, const float* __restrict__ g,
                        const float* __restrict__ bb, const float* __restrict__ W2,
                        const float* __restrict__ b2, float* __restrict__ out) {
    int e = blockIdx.x * blockDim.x + threadIdx.x;
    if (e >= E_) return;
    float acc = b2[0];
#pragma unroll 4
    for (int j = 0; j < 128; j++) {
        float v = (h1[(size_t)e * 128 + j] - mu[j]) * rsig[j] * g[j] + bb[j];
        acc += fmaxf(v, 0.f) * W2[j];
    }
    out[(size_t)E_ * 242 + e] = acc;
}

extern "C" void kernel_launch(void* const* d_in, const int* in_sizes, int n_in,
                              void* d_out, int out_size, void* d_ws, size_t ws_size,
                              hipStream_t stream) {
    const int*   x        = (const int*)  d_in[0];
    const float* pos      = (const float*)d_in[1];
    const int*   ei       = (const int*)  d_in[2];
    const float* edge_atr = (const float*)d_in[3];
    const float* emb      = (const float*)d_in[4];
    const float* lin0_W   = (const float*)d_in[5];
    const float* lin0_b   = (const float*)d_in[6];
    const float* mlp1_W   = (const float*)d_in[7];
    const float* mlp1_b   = (const float*)d_in[8];
    const float* mlp2_W   = (const float*)d_in[9];
    const float* mlp2_b   = (const float*)d_in[10];
    const float* conv_b   = (const float*)d_in[11];
    const float* gru_Wih  = (const float*)d_in[12];
    const float* gru_Whh  = (const float*)d_in[13];
    const float* gru_bih  = (const float*)d_in[14];
    const float* gru_bhh  = (const float*)d_in[15];
    const float* lin1_W   = (const float*)d_in[16];
    const float* lin1_b   = (const float*)d_in[17];
    const float* lin2_W   = (const float*)d_in[18];
    const float* lin2_b   = (const float*)d_in[19];
    const float* l6_W1    = (const float*)d_in[20];
    const float* l6_b1    = (const float*)d_in[21];
    const float* bn_g     = (const float*)d_in[22];
    const float* bn_b     = (const float*)d_in[23];
    const float* l6_W2    = (const float*)d_in[24];
    const float* l6_b2    = (const float*)d_in[25];
    float* out = (float*)d_out;

    // workspace layout
    char* w = (char*)d_ws;
    size_t off = 0;
    auto alloc = [&](size_t bytes) -> void* {
        void* p = w + off;
        off = (off + bytes + 255) & ~(size_t)255;
        return p;
    };
    float* hbuf   = (float*)alloc((size_t)N_ * H_ * 4);
    float* aggm   = (float*)alloc((size_t)N_ * H_ * 4);   // agg, then m in place
    float* outb   = (float*)alloc((size_t)N_ * H_ * 4);
    float* he     = (float*)alloc((size_t)E_ * KH_ * 4);
    float* gi     = (float*)alloc((size_t)N_ * 768 * 4);
    float* gh     = (float*)alloc((size_t)N_ * 768 * 4);
    float* o1     = (float*)alloc((size_t)E_ * H_ * 4);
    float* h1     = (float*)alloc((size_t)E_ * 128 * 4);
    float* counts = (float*)alloc((size_t)N_ * 4);
    float* mu     = (float*)alloc(128 * 4);
    float* rsig   = (float*)alloc(128 * 4);
    __hip_bfloat16* V   = (__hip_bfloat16*)alloc((size_t)N_ * NV_ * 2);     // 131 MB
    __hip_bfloat16* Abf = (__hip_bfloat16*)alloc((size_t)MPAD_ * H_ * 2);   // 1 MB
    __hip_bfloat16* Bt  = (__hip_bfloat16*)alloc((size_t)NV_ * H_ * 2);     // 16.8 MB

    k_lin0<<<N_, 256, 0, stream>>>(x, pos, emb, lin0_W, lin0_b, hbuf);
    k_he<<<E_, 128, 0, stream>>>(edge_atr, mlp1_W, mlp1_b, he);
    hipMemsetAsync(counts, 0, (size_t)N_ * 4, stream);
    k_counts<<<(E_ + 255) / 256, 256, 0, stream>>>(ei, counts);
    k_trans_bt<<<dim3(NV_ / 64, H_ / 32), 256, 0, stream>>>(mlp2_W, Bt);

    for (int it = 0; it < 3; it++) {
        k_outb<<<N_, 256, 0, stream>>>(hbuf, mlp2_b, outb);
        k_abf<<<MPAD_, 256, 0, stream>>>(hbuf, Abf);
        dim3 gv(NV_ / 128, MPAD_ / 128);
        k_gemm_V_mfma<<<gv, 256, 0, stream>>>(Abf, Bt, V);
        hipMemsetAsync(aggm, 0, (size_t)N_ * H_ * 4, stream);
        k_msg<<<E_, 256, 0, stream>>>(ei, he, V, outb, aggm);
        k_m<<<(N_ * H_ + 255) / 256, 256, 0, stream>>>(aggm, counts, conv_b);
        k_gru_gemm<<<dim3(N_, 3), 256, 0, stream>>>(aggm, hbuf, gru_Wih, gru_Whh,
                                                    gru_bih, gru_bhh, gi, gh);
        k_gru_update<<<(N_ * H_ + 255) / 256, 256, 0, stream>>>(gi, gh, hbuf);
    }

    k_o1<<<E_, 256, 0, stream>>>(ei, hbuf, lin1_W, lin1_b, o1);
    k_out2<<<E_, 256, 0, stream>>>(o1, lin2_W, lin2_b, out);
    k_h1<<<E_, 128, 0, stream>>>(ei, hbuf, l6_W1, l6_b1, h1);
    k_bnstats<<<128, 256, 0, stream>>>(h1, mu, rsig);
    k_precs<<<(E_ + 255) / 256, 256, 0, stream>>>(h1, mu, rsig, bn_g, bn_b, l6_W2, l6_b2, out);
}

// Round 3
// 1056.335 us; speedup vs baseline: 3.1862x; 1.9177x over previous
//
#include <hip/hip_runtime.h>
#include <hip/hip_bf16.h>

// Problem constants (fixed by the reference)
constexpr int N_ = 2000;   // nodes
constexpr int E_ = 4096;   // edges
constexpr int H_ = 256;    // hidden
constexpr int KH_ = 128;   // he dim (mlp1 out)
constexpr int NV_ = H_ * KH_; // 32768, V row length (layout [o*128+k])
constexpr int MPAD_ = 2048;   // padded M for the MFMA GEMM
constexpr int NG_ = 768;      // GRU gate width (3*H)

typedef short bf16x8 __attribute__((ext_vector_type(8)));
typedef float f32x4  __attribute__((ext_vector_type(4)));

__device__ __forceinline__ float bf_lo(unsigned u) { return __uint_as_float(u << 16); }
__device__ __forceinline__ float bf_hi(unsigned u) { return __uint_as_float(u & 0xffff0000u); }

// out = relu([emb[x], pos] @ lin0_W.T + b)   grid N, block 256
__global__ void k_lin0(const int* __restrict__ x, const float* __restrict__ pos,
                       const float* __restrict__ emb, const float* __restrict__ W,
                       const float* __restrict__ b, float* __restrict__ out) {
    int n = blockIdx.x, t = threadIdx.x;
    __shared__ float in_p[8];
    if (t < 5) in_p[t] = emb[x[n] * 5 + t];
    else if (t < 8) in_p[t] = pos[n * 3 + (t - 5)];
    __syncthreads();
    float acc = b[t];
#pragma unroll
    for (int i = 0; i < 8; i++) acc += in_p[i] * W[t * 8 + i];
    out[n * H_ + t] = fmaxf(acc, 0.f);
}

// he = relu(edge_atr @ mlp1_W.T + b)   grid E, block 128
__global__ void k_he(const float* __restrict__ ea, const float* __restrict__ W,
                     const float* __restrict__ b, float* __restrict__ he) {
    int e = blockIdx.x, t = threadIdx.x;
    __shared__ float a[5];
    if (t < 5) a[t] = ea[e * 5 + t];
    __syncthreads();
    float acc = b[t];
#pragma unroll
    for (int i = 0; i < 5; i++) acc += a[i] * W[t * 5 + i];
    he[e * KH_ + t] = fmaxf(acc, 0.f);
}

__global__ void k_counts(const int* __restrict__ ei, float* __restrict__ counts) {
    int e = blockIdx.x * blockDim.x + threadIdx.x;
    if (e < E_) atomicAdd(&counts[ei[E_ + e]], 1.0f);
}

// outb[n,o] = sum_h out[n,h] * mlp2_b[h*256+o]   grid N, block 256
__global__ void k_outb(const float* __restrict__ hbuf, const float* __restrict__ b2,
                       float* __restrict__ outb) {
    int n = blockIdx.x, o = threadIdx.x;
    __shared__ float hr[H_];
    hr[o] = hbuf[n * H_ + o];
    __syncthreads();
    float acc = 0.f;
    for (int h = 0; h < H_; h++) acc += hr[h] * b2[h * H_ + o];
    outb[n * H_ + o] = acc;
}

// Bt[n][k] = mlp2_W[k*32768 + n] as bf16 (transpose+convert), once per launch.
// grid (512, 8), block 256; tile 32k x 64n via LDS.
__global__ void k_trans_bt(const float* __restrict__ W, __hip_bfloat16* __restrict__ Bt) {
    __shared__ float tile[32][65];
    int t = threadIdx.x;
    int n0 = blockIdx.x * 64, k0 = blockIdx.y * 32;
#pragma unroll
    for (int i = 0; i < 8; i++) {
        int idx = t + i * 256;
        int kk = idx >> 6, nn = idx & 63;
        tile[kk][nn] = W[(size_t)(k0 + kk) * NV_ + n0 + nn];
    }
    __syncthreads();
#pragma unroll
    for (int i = 0; i < 8; i++) {
        int idx = t + i * 256;
        int nn = idx >> 5, kk = idx & 31;
        Bt[(size_t)(n0 + nn) * H_ + k0 + kk] = __float2bfloat16(tile[kk][nn]);
    }
}

// Abf[n][k] = bf16(hbuf[n][k]) for n<2000, garbage-safe pad.  grid 2048, block 256
__global__ void k_abf(const float* __restrict__ hbuf, __hip_bfloat16* __restrict__ Abf) {
    int i = blockIdx.x * 256 + threadIdx.x;
    int n = i >> 8;
    Abf[i] = (n < N_) ? __float2bfloat16(hbuf[i]) : __float2bfloat16(0.f);
}

// fp32 -> bf16 elementwise for the two GRU weight matrices (once per launch)
__global__ void k_wbf(const float* __restrict__ Wih, const float* __restrict__ Whh,
                      __hip_bfloat16* __restrict__ Wih_b, __hip_bfloat16* __restrict__ Whh_b) {
    int i = blockIdx.x * 256 + threadIdx.x;
    if (i < NG_ * H_) {
        Wih_b[i] = __float2bfloat16(Wih[i]);
        Whh_b[i] = __float2bfloat16(Whh[i]);
    }
}

// V = Abf(2048x256 bf16) @ Bt^T(32768x256 bf16, n-major) -> bf16, MFMA 16x16x32.
// 128x128 block tile, 4 waves (2x2), each wave 4x4 of 16x16 tiles. BK=32.
__global__ __launch_bounds__(256) void k_gemm_V_mfma(const __hip_bfloat16* __restrict__ A,
                                                     const __hip_bfloat16* __restrict__ Bt,
                                                     __hip_bfloat16* __restrict__ C) {
    __shared__ short As[128 * 32];
    __shared__ short Bs[128 * 32];
    int t = threadIdx.x;
    int lane = t & 63, wave = t >> 6;
    int wm = wave >> 1, wn = wave & 1;
    int quad = lane >> 4, l16 = lane & 15;
    int row0 = blockIdx.y * 128, col0 = blockIdx.x * 128;

    f32x4 acc[4][4] = {};
    int r_ld = (lane >> 2);
    int koff = (lane & 3) * 8;

    for (int k0 = 0; k0 < H_; k0 += 32) {
#pragma unroll
        for (int c = 0; c < 4; c++) {
            int q = wave * 4 + c;
            int ch = q & 7;
            int r = ch * 16 + r_ld;
            const __hip_bfloat16* gp;
            short* lp;
            if (q < 8) { gp = A  + ((size_t)(row0 + r) << 8) + k0 + koff; lp = As + ch * 512; }
            else       { gp = Bt + ((size_t)(col0 + r) << 8) + k0 + koff; lp = Bs + ch * 512; }
            __builtin_amdgcn_global_load_lds(
                (const __attribute__((address_space(1))) unsigned int*)(uintptr_t)gp,
                (__attribute__((address_space(3))) unsigned int*)(uintptr_t)lp,
                16, 0, 0);
        }
        __syncthreads();
        bf16x8 a[4], b[4];
#pragma unroll
        for (int i = 0; i < 4; i++)
            a[i] = *(const bf16x8*)&As[(wm * 64 + i * 16 + l16) * 32 + quad * 8];
#pragma unroll
        for (int j = 0; j < 4; j++)
            b[j] = *(const bf16x8*)&Bs[(wn * 64 + j * 16 + l16) * 32 + quad * 8];
#pragma unroll
        for (int i = 0; i < 4; i++)
#pragma unroll
            for (int j = 0; j < 4; j++)
                acc[i][j] = __builtin_amdgcn_mfma_f32_16x16x32_bf16(a[i], b[j], acc[i][j], 0, 0, 0);
        __syncthreads();
    }

#pragma unroll
    for (int i = 0; i < 4; i++) {
        int gm0 = row0 + wm * 64 + i * 16 + quad * 4;
#pragma unroll
        for (int r = 0; r < 4; r++) {
            int gm = gm0 + r;
            if (gm < N_) {
                size_t base = (size_t)gm * NV_ + col0 + wn * 64 + l16;
#pragma unroll
                for (int j = 0; j < 4; j++)
                    C[base + j * 16] = __float2bfloat16(acc[i][j][r]);
            }
        }
    }
}

// GRU gates GEMM on MFMA: z=0 -> gi = Mbf @ Wih_b^T + bih; z=1 -> gh = Abf(h) @ Whh_b^T + bhh.
// M=2048(pad), K=256, N=768. Same tile structure as k_gemm_V_mfma; fp32 out + bias.
__global__ __launch_bounds__(256) void k_gemm_gru_mfma(const __hip_bfloat16* __restrict__ A0,
                                                       const __hip_bfloat16* __restrict__ A1,
                                                       const __hip_bfloat16* __restrict__ W0,
                                                       const __hip_bfloat16* __restrict__ W1,
                                                       const float* __restrict__ b0,
                                                       const float* __restrict__ b1,
                                                       float* __restrict__ C0,
                                                       float* __restrict__ C1) {
    __shared__ short As[128 * 32];
    __shared__ short Bs[128 * 32];
    int t = threadIdx.x;
    int lane = t & 63, wave = t >> 6;
    int wm = wave >> 1, wn = wave & 1;
    int quad = lane >> 4, l16 = lane & 15;
    int row0 = blockIdx.y * 128, col0 = blockIdx.x * 128;
    const __hip_bfloat16* A  = blockIdx.z ? A1 : A0;
    const __hip_bfloat16* Bt = blockIdx.z ? W1 : W0;
    const float* bias        = blockIdx.z ? b1 : b0;
    float* C                 = blockIdx.z ? C1 : C0;

    f32x4 acc[4][4] = {};
    int r_ld = (lane >> 2);
    int koff = (lane & 3) * 8;

    for (int k0 = 0; k0 < H_; k0 += 32) {
#pragma unroll
        for (int c = 0; c < 4; c++) {
            int q = wave * 4 + c;
            int ch = q & 7;
            int r = ch * 16 + r_ld;
            const __hip_bfloat16* gp;
            short* lp;
            if (q < 8) { gp = A  + ((size_t)(row0 + r) << 8) + k0 + koff; lp = As + ch * 512; }
            else       { gp = Bt + ((size_t)(col0 + r) << 8) + k0 + koff; lp = Bs + ch * 512; }
            __builtin_amdgcn_global_load_lds(
                (const __attribute__((address_space(1))) unsigned int*)(uintptr_t)gp,
                (__attribute__((address_space(3))) unsigned int*)(uintptr_t)lp,
                16, 0, 0);
        }
        __syncthreads();
        bf16x8 a[4], b[4];
#pragma unroll
        for (int i = 0; i < 4; i++)
            a[i] = *(const bf16x8*)&As[(wm * 64 + i * 16 + l16) * 32 + quad * 8];
#pragma unroll
        for (int j = 0; j < 4; j++)
            b[j] = *(const bf16x8*)&Bs[(wn * 64 + j * 16 + l16) * 32 + quad * 8];
#pragma unroll
        for (int i = 0; i < 4; i++)
#pragma unroll
            for (int j = 0; j < 4; j++)
                acc[i][j] = __builtin_amdgcn_mfma_f32_16x16x32_bf16(a[i], b[j], acc[i][j], 0, 0, 0);
        __syncthreads();
    }

#pragma unroll
    for (int i = 0; i < 4; i++) {
        int gm0 = row0 + wm * 64 + i * 16 + quad * 4;
#pragma unroll
        for (int r = 0; r < 4; r++) {
            int gm = gm0 + r;
            if (gm < N_) {
                int col = col0 + wn * 64 + l16;
                size_t base = (size_t)gm * NG_ + col;
#pragma unroll
                for (int j = 0; j < 4; j++)
                    C[base + j * 16] = acc[i][j][r] + bias[col + j * 16];
            }
        }
    }
}

// msg[e,o] = he[e,:].V[row[e],o,:] + outb[row[e],o]; atomicAdd into agg[col[e],o]
__global__ void k_msg(const int* __restrict__ ei, const float* __restrict__ he,
                      const __hip_bfloat16* __restrict__ V, const float* __restrict__ outb,
                      float* __restrict__ agg) {
    int e = blockIdx.x, o = threadIdx.x;
    __shared__ float hs[KH_];
    if (o < KH_) hs[o] = he[e * KH_ + o];
    __syncthreads();
    int r = ei[e], c = ei[E_ + e];
    float acc = outb[(size_t)r * H_ + o];
    const uint4* vp4 = reinterpret_cast<const uint4*>(V + (size_t)r * NV_ + (size_t)o * KH_);
#pragma unroll
    for (int q = 0; q < KH_ / 8; q++) {
        uint4 u = vp4[q];
        const float* hp = hs + q * 8;
        acc += hp[0] * bf_lo(u.x) + hp[1] * bf_hi(u.x)
             + hp[2] * bf_lo(u.y) + hp[3] * bf_hi(u.y)
             + hp[4] * bf_lo(u.z) + hp[5] * bf_hi(u.z)
             + hp[6] * bf_lo(u.w) + hp[7] * bf_hi(u.w);
    }
    atomicAdd(&agg[(size_t)c * H_ + o], acc);
}

// Mbf = bf16(relu(agg / max(counts,1) + conv_b))
__global__ void k_m(const float* __restrict__ agg, const float* __restrict__ counts,
                    const float* __restrict__ conv_b, __hip_bfloat16* __restrict__ Mbf) {
    int i = blockIdx.x * blockDim.x + threadIdx.x;
    if (i >= N_ * H_) return;
    int n = i >> 8, o = i & 255;
    float c = fmaxf(counts[n], 1.0f);
    Mbf[i] = __float2bfloat16(fmaxf(agg[i] / c + conv_b[o], 0.f));
}

__global__ void k_gru_update(const float* __restrict__ gi, const float* __restrict__ gh,
                             float* __restrict__ h) {
    int i = blockIdx.x * blockDim.x + threadIdx.x;
    if (i >= N_ * H_) return;
    int n = i >> 8, j = i & 255;
    const float* gip = gi + (size_t)n * NG_;
    const float* ghp = gh + (size_t)n * NG_;
    float r = 1.f / (1.f + expf(-(gip[j] + ghp[j])));
    float z = 1.f / (1.f + expf(-(gip[H_ + j] + ghp[H_ + j])));
    float nn = tanhf(gip[2 * H_ + j] + r * ghp[2 * H_ + j]);
    h[i] = (1.f - z) * nn + z * h[i];
}

// o1 = relu([h[row],h[col]] @ lin1_W.T + b)   grid E, block 256
__global__ void k_o1(const int* __restrict__ ei, const float* __restrict__ h,
                     const float* __restrict__ W, const float* __restrict__ b,
                     float* __restrict__ o1) {
    int e = blockIdx.x, t = threadIdx.x;
    __shared__ float oc[2 * H_];
    int r = ei[e], c = ei[E_ + e];
    oc[t] = h[(size_t)r * H_ + t];
    oc[H_ + t] = h[(size_t)c * H_ + t];
    __syncthreads();
    const float4* w4 = reinterpret_cast<const float4*>(W + (size_t)t * 2 * H_);
    float acc = b[t];
#pragma unroll 4
    for (int k4 = 0; k4 < 2 * H_ / 4; k4++) {
        float4 a = w4[k4];
        acc += oc[k4 * 4 + 0] * a.x + oc[k4 * 4 + 1] * a.y + oc[k4 * 4 + 2] * a.z + oc[k4 * 4 + 3] * a.w;
    }
    o1[(size_t)e * H_ + t] = fmaxf(acc, 0.f);
}

// out2 = o1 @ lin2_W.T + b (242 cols)   grid E, block 256
__global__ void k_out2(const float* __restrict__ o1, const float* __restrict__ W,
                       const float* __restrict__ b, float* __restrict__ out) {
    int e = blockIdx.x, t = threadIdx.x;
    __shared__ float os[H_];
    os[t] = o1[(size_t)e * H_ + t];
    __syncthreads();
    if (t < 242) {
        const float4* w4 = reinterpret_cast<const float4*>(W + (size_t)t * H_);
        float acc = b[t];
#pragma unroll 4
        for (int k4 = 0; k4 < H_ / 4; k4++) {
            float4 a = w4[k4];
            acc += os[k4 * 4 + 0] * a.x + os[k4 * 4 + 1] * a.y + os[k4 * 4 + 2] * a.z + os[k4 * 4 + 3] * a.w;
        }
        out[(size_t)e * 242 + t] = acc;
    }
}

// h1 = [h[row],h[col]] @ l6_W1.T + b (128 cols)   grid E, block 128
__global__ void k_h1(const int* __restrict__ ei, const float* __restrict__ h,
                     const float* __restrict__ W, const float* __restrict__ b,
                     float* __restrict__ h1) {
    int e = blockIdx.x, t = threadIdx.x;
    __shared__ float oc[2 * H_];
    int r = ei[e], c = ei[E_ + e];
    oc[t] = h[(size_t)r * H_ + t];
    oc[t + 128] = h[(size_t)r * H_ + t + 128];
    oc[H_ + t] = h[(size_t)c * H_ + t];
    oc[H_ + t + 128] = h[(size_t)c * H_ + t + 128];
    __syncthreads();
    const float4* w4 = reinterpret_cast<const float4*>(W + (size_t)t * 2 * H_);
    float acc = b[t];
#pragma unroll 4
    for (int k4 = 0; k4 < 2 * H_ / 4; k4++) {
        float4 a = w4[k4];
        acc += oc[k4 * 4 + 0] * a.x + oc[k4 * 4 + 1] * a.y + oc[k4 * 4 + 2] * a.z + oc[k4 * 4 + 3] * a.w;
    }
    h1[(size_t)e * 128 + t] = acc;
}

// batchnorm stats over E rows, per column j   grid 128, block 256
__global__ void k_bnstats(const float* __restrict__ h1, float* __restrict__ mu,
                          float* __restrict__ rsig) {
    int j = blockIdx.x, t = threadIdx.x;
    float s = 0.f, ss = 0.f;
    for (int e = t; e < E_; e += 256) {
        float v = h1[(size_t)e * 128 + j];
        s += v;
        ss += v * v;
    }
    __shared__ float rs[256], rss[256];
    rs[t] = s; rss[t] = ss;
    __syncthreads();
    for (int off = 128; off > 0; off >>= 1) {
        if (t < off) { rs[t] += rs[t + off]; rss[t] += rss[t + off]; }
        __syncthreads();
    }
    if (t == 0) {
        float m_ = rs[0] / E_;
        float v_ = rss[0] / E_ - m_ * m_;
        mu[j] = m_;
        rsig[j] = rsqrtf(v_ + 1e-5f);
    }
}

// precs[e] = relu(bn(h1[e])) . l6_W2 + b
__global__ void k_precs(const float* __restrict__ h1, const float* __restrict__ mu,
                        const float* __restrict__ rsig, const float* __restrict__ g,
                        const float* __restrict__ bb, const float* __restrict__ W2,
                        const float* __restrict__ b2, float* __restrict__ out) {
    int e = blockIdx.x * blockDim.x + threadIdx.x;
    if (e >= E_) return;
    float acc = b2[0];
#pragma unroll 4
    for (int j = 0; j < 128; j++) {
        float v = (h1[(size_t)e * 128 + j] - mu[j]) * rsig[j] * g[j] + bb[j];
        acc += fmaxf(v, 0.f) * W2[j];
    }
    out[(size_t)E_ * 242 + e] = acc;
}

extern "C" void kernel_launch(void* const* d_in, const int* in_sizes, int n_in,
                              void* d_out, int out_size, void* d_ws, size_t ws_size,
                              hipStream_t stream) {
    const int*   x        = (const int*)  d_in[0];
    const float* pos      = (const float*)d_in[1];
    const int*   ei       = (const int*)  d_in[2];
    const float* edge_atr = (const float*)d_in[3];
    const float* emb      = (const float*)d_in[4];
    const float* lin0_W   = (const float*)d_in[5];
    const float* lin0_b   = (const float*)d_in[6];
    const float* mlp1_W   = (const float*)d_in[7];
    const float* mlp1_b   = (const float*)d_in[8];
    const float* mlp2_W   = (const float*)d_in[9];
    const float* mlp2_b   = (const float*)d_in[10];
    const float* conv_b   = (const float*)d_in[11];
    const float* gru_Wih  = (const float*)d_in[12];
    const float* gru_Whh  = (const float*)d_in[13];
    const float* gru_bih  = (const float*)d_in[14];
    const float* gru_bhh  = (const float*)d_in[15];
    const float* lin1_W   = (const float*)d_in[16];
    const float* lin1_b   = (const float*)d_in[17];
    const float* lin2_W   = (const float*)d_in[18];
    const float* lin2_b   = (const float*)d_in[19];
    const float* l6_W1    = (const float*)d_in[20];
    const float* l6_b1    = (const float*)d_in[21];
    const float* bn_g     = (const float*)d_in[22];
    const float* bn_b     = (const float*)d_in[23];
    const float* l6_W2    = (const float*)d_in[24];
    const float* l6_b2    = (const float*)d_in[25];
    float* out = (float*)d_out;

    // workspace layout
    char* w = (char*)d_ws;
    size_t off = 0;
    auto alloc = [&](size_t bytes) -> void* {
        void* p = w + off;
        off = (off + bytes + 255) & ~(size_t)255;
        return p;
    };
    float* hbuf   = (float*)alloc((size_t)N_ * H_ * 4);
    float* aggm   = (float*)alloc((size_t)N_ * H_ * 4);
    float* outb   = (float*)alloc((size_t)N_ * H_ * 4);
    float* he     = (float*)alloc((size_t)E_ * KH_ * 4);
    float* gi     = (float*)alloc((size_t)N_ * NG_ * 4);
    float* gh     = (float*)alloc((size_t)N_ * NG_ * 4);
    float* o1     = (float*)alloc((size_t)E_ * H_ * 4);
    float* h1     = (float*)alloc((size_t)E_ * 128 * 4);
    float* counts = (float*)alloc((size_t)N_ * 4);
    float* mu     = (float*)alloc(128 * 4);
    float* rsig   = (float*)alloc(128 * 4);
    __hip_bfloat16* V     = (__hip_bfloat16*)alloc((size_t)N_ * NV_ * 2);     // 131 MB
    __hip_bfloat16* Abf   = (__hip_bfloat16*)alloc((size_t)MPAD_ * H_ * 2);   // h in bf16
    __hip_bfloat16* Mbf   = (__hip_bfloat16*)alloc((size_t)MPAD_ * H_ * 2);   // m in bf16
    __hip_bfloat16* Bt    = (__hip_bfloat16*)alloc((size_t)NV_ * H_ * 2);     // 16.8 MB
    __hip_bfloat16* WihB  = (__hip_bfloat16*)alloc((size_t)NG_ * H_ * 2);
    __hip_bfloat16* WhhB  = (__hip_bfloat16*)alloc((size_t)NG_ * H_ * 2);

    k_lin0<<<N_, 256, 0, stream>>>(x, pos, emb, lin0_W, lin0_b, hbuf);
    k_he<<<E_, 128, 0, stream>>>(edge_atr, mlp1_W, mlp1_b, he);
    hipMemsetAsync(counts, 0, (size_t)N_ * 4, stream);
    k_counts<<<(E_ + 255) / 256, 256, 0, stream>>>(ei, counts);
    k_trans_bt<<<dim3(NV_ / 64, H_ / 32), 256, 0, stream>>>(mlp2_W, Bt);
    k_wbf<<<(NG_ * H_ + 255) / 256, 256, 0, stream>>>(gru_Wih, gru_Whh, WihB, WhhB);

    for (int it = 0; it < 3; it++) {
        k_outb<<<N_, 256, 0, stream>>>(hbuf, mlp2_b, outb);
        k_abf<<<MPAD_, 256, 0, stream>>>(hbuf, Abf);
        dim3 gv(NV_ / 128, MPAD_ / 128);
        k_gemm_V_mfma<<<gv, 256, 0, stream>>>(Abf, Bt, V);
        hipMemsetAsync(aggm, 0, (size_t)N_ * H_ * 4, stream);
        k_msg<<<E_, 256, 0, stream>>>(ei, he, V, outb, aggm);
        k_m<<<(N_ * H_ + 255) / 256, 256, 0, stream>>>(aggm, counts, conv_b, Mbf);
        dim3 gg(NG_ / 128, MPAD_ / 128, 2);
        k_gemm_gru_mfma<<<gg, 256, 0, stream>>>(Mbf, Abf, WihB, WhhB,
                                                gru_bih, gru_bhh, gi, gh);
        k_gru_update<<<(N_ * H_ + 255) / 256, 256, 0, stream>>>(gi, gh, hbuf);
    }

    k_o1<<<E_, 256, 0, stream>>>(ei, hbuf, lin1_W, lin1_b, o1);
    k_out2<<<E_, 256, 0, stream>>>(o1, lin2_W, lin2_b, out);
    k_h1<<<E_, 128, 0, stream>>>(ei, hbuf, l6_W1, l6_b1, h1);
    k_bnstats<<<128, 256, 0, stream>>>(h1, mu, rsig);
    k_precs<<<(E_ + 255) / 256, 256, 0, stream>>>(h1, mu, rsig, bn_g, bn_b, l6_W2, l6_b2, out);
}

// Round 4
// 638.705 us; speedup vs baseline: 5.2696x; 1.6539x over previous
//
#include <hip/hip_runtime.h>
#include <hip/hip_bf16.h>

// Problem constants (fixed by the reference)
constexpr int N_ = 2000;   // nodes
constexpr int E_ = 4096;   // edges
constexpr int H_ = 256;    // hidden
constexpr int KH_ = 128;   // he dim (mlp1 out)
constexpr int NV_ = H_ * KH_; // 32768, V row length (layout [o*128+k])
constexpr int MPAD_ = 2048;   // padded M for node-side MFMA GEMMs
constexpr int NG_ = 768;      // GRU gate width (3*H)

typedef short bf16x8 __attribute__((ext_vector_type(8)));
typedef float f32x4  __attribute__((ext_vector_type(4)));

__device__ __forceinline__ float bf_lo(unsigned u) { return __uint_as_float(u << 16); }
__device__ __forceinline__ float bf_hi(unsigned u) { return __uint_as_float(u & 0xffff0000u); }

// out = relu([emb[x], pos] @ lin0_W.T + b)   grid N, block 256
__global__ void k_lin0(const int* __restrict__ x, const float* __restrict__ pos,
                       const float* __restrict__ emb, const float* __restrict__ W,
                       const float* __restrict__ b, float* __restrict__ out) {
    int n = blockIdx.x, t = threadIdx.x;
    __shared__ float in_p[8];
    if (t < 5) in_p[t] = emb[x[n] * 5 + t];
    else if (t < 8) in_p[t] = pos[n * 3 + (t - 5)];
    __syncthreads();
    float acc = b[t];
#pragma unroll
    for (int i = 0; i < 8; i++) acc += in_p[i] * W[t * 8 + i];
    out[n * H_ + t] = fmaxf(acc, 0.f);
}

// he = relu(edge_atr @ mlp1_W.T + b)   grid E, block 128
__global__ void k_he(const float* __restrict__ ea, const float* __restrict__ W,
                     const float* __restrict__ b, float* __restrict__ he) {
    int e = blockIdx.x, t = threadIdx.x;
    __shared__ float a[5];
    if (t < 5) a[t] = ea[e * 5 + t];
    __syncthreads();
    float acc = b[t];
#pragma unroll
    for (int i = 0; i < 5; i++) acc += a[i] * W[t * 5 + i];
    he[e * KH_ + t] = fmaxf(acc, 0.f);
}

__global__ void k_counts(const int* __restrict__ ei, float* __restrict__ counts) {
    int e = blockIdx.x * blockDim.x + threadIdx.x;
    if (e < E_) atomicAdd(&counts[ei[E_ + e]], 1.0f);
}

// Bt[n][k] = mlp2_W[k*32768 + n] as bf16 (transpose+convert), once per launch.
__global__ void k_trans_bt(const float* __restrict__ W, __hip_bfloat16* __restrict__ Bt) {
    __shared__ float tile[32][65];
    int t = threadIdx.x;
    int n0 = blockIdx.x * 64, k0 = blockIdx.y * 32;
#pragma unroll
    for (int i = 0; i < 8; i++) {
        int idx = t + i * 256;
        int kk = idx >> 6, nn = idx & 63;
        tile[kk][nn] = W[(size_t)(k0 + kk) * NV_ + n0 + nn];
    }
    __syncthreads();
#pragma unroll
    for (int i = 0; i < 8; i++) {
        int idx = t + i * 256;
        int nn = idx >> 5, kk = idx & 31;
        Bt[(size_t)(n0 + nn) * H_ + k0 + kk] = __float2bfloat16(tile[kk][nn]);
    }
}

// One-time weight preps: GRU weights, lin1_W, l6_W1, lin2_W (padded 242->256 rows),
// BtB[o][h] = bf16(mlp2_b[h*256+o]).   grid 768, block 256
__global__ void k_prep_w(const float* __restrict__ Wih, const float* __restrict__ Whh,
                         const float* __restrict__ lin1W, const float* __restrict__ l6W1,
                         const float* __restrict__ lin2W, const float* __restrict__ b2,
                         __hip_bfloat16* __restrict__ WihB, __hip_bfloat16* __restrict__ WhhB,
                         __hip_bfloat16* __restrict__ lin1Wb, __hip_bfloat16* __restrict__ l6W1b,
                         __hip_bfloat16* __restrict__ lin2Wb, __hip_bfloat16* __restrict__ BtB) {
    int i = blockIdx.x * 256 + threadIdx.x;
    if (i < NG_ * H_) {                        // 196608
        WihB[i] = __float2bfloat16(Wih[i]);
        WhhB[i] = __float2bfloat16(Whh[i]);
    }
    if (i < H_ * 2 * H_) {                     // 131072
        lin1Wb[i] = __float2bfloat16(lin1W[i]);
    }
    if (i < 128 * 2 * H_) {                    // 65536
        l6W1b[i] = __float2bfloat16(l6W1[i]);
        int r = i >> 8, k = i & 255;           // lin2 padded: rows 242..255 = 0
        lin2Wb[i] = __float2bfloat16(r < 242 ? lin2W[r * H_ + k] : 0.f);
        int o = i >> 8, h = i & 255;           // transpose of mlp2_b (h-major -> o-major)
        BtB[o * H_ + h] = __float2bfloat16(b2[h * H_ + o]);
    }
}

// Abf[n][k] = bf16(hbuf[n][k]) for n<2000, zero pad.  grid 2048, block 256
__global__ void k_abf(const float* __restrict__ hbuf, __hip_bfloat16* __restrict__ Abf) {
    int i = blockIdx.x * 256 + threadIdx.x;
    int n = i >> 8;
    Abf[i] = (n < N_) ? __float2bfloat16(hbuf[i]) : __float2bfloat16(0.f);
}

// Cbf[e] = bf16([h[row[e]], h[col[e]]])   grid E, block 256
__global__ void k_concat(const int* __restrict__ ei, const float* __restrict__ h,
                         __hip_bfloat16* __restrict__ Cbf) {
    int e = blockIdx.x, t = threadIdx.x;
    int r = ei[e], c = ei[E_ + e];
    Cbf[(size_t)e * 512 + t]       = __float2bfloat16(h[(size_t)r * H_ + t]);
    Cbf[(size_t)e * 512 + 256 + t] = __float2bfloat16(h[(size_t)c * H_ + t]);
}

// Generic MFMA GEMM: C(MxN) = A(MxKD bf16) @ Bt(NxKD bf16)^T [+bias][relu].
// 128x128 tile, 4 waves, BK=32. grid (ceil(N/128), M/128).
template <int KD, bool RELU, bool OUT_BF16>
__global__ __launch_bounds__(256) void k_gemm_nt(const __hip_bfloat16* __restrict__ A,
                                                 const __hip_bfloat16* __restrict__ Bt,
                                                 float* __restrict__ Cf,
                                                 __hip_bfloat16* __restrict__ Cb,
                                                 const float* __restrict__ bias,
                                                 int ldc, int ncols, int mvalid) {
    __shared__ short As[128 * 32];
    __shared__ short Bs[128 * 32];
    int t = threadIdx.x;
    int lane = t & 63, wave = t >> 6;
    int wm = wave >> 1, wn = wave & 1;
    int quad = lane >> 4, l16 = lane & 15;
    int row0 = blockIdx.y * 128, col0 = blockIdx.x * 128;

    f32x4 acc[4][4] = {};
    int r_ld = (lane >> 2);
    int koff = (lane & 3) * 8;

    for (int k0 = 0; k0 < KD; k0 += 32) {
#pragma unroll
        for (int c = 0; c < 4; c++) {
            int q = wave * 4 + c;
            int ch = q & 7;
            int r = ch * 16 + r_ld;
            const __hip_bfloat16* gp;
            short* lp;
            if (q < 8) { gp = A  + (size_t)(row0 + r) * KD + k0 + koff; lp = As + ch * 512; }
            else       { gp = Bt + (size_t)(col0 + r) * KD + k0 + koff; lp = Bs + ch * 512; }
            __builtin_amdgcn_global_load_lds(
                (const __attribute__((address_space(1))) unsigned int*)(uintptr_t)gp,
                (__attribute__((address_space(3))) unsigned int*)(uintptr_t)lp,
                16, 0, 0);
        }
        __syncthreads();
        bf16x8 a[4], b[4];
#pragma unroll
        for (int i = 0; i < 4; i++)
            a[i] = *(const bf16x8*)&As[(wm * 64 + i * 16 + l16) * 32 + quad * 8];
#pragma unroll
        for (int j = 0; j < 4; j++)
            b[j] = *(const bf16x8*)&Bs[(wn * 64 + j * 16 + l16) * 32 + quad * 8];
#pragma unroll
        for (int i = 0; i < 4; i++)
#pragma unroll
            for (int j = 0; j < 4; j++)
                acc[i][j] = __builtin_amdgcn_mfma_f32_16x16x32_bf16(a[i], b[j], acc[i][j], 0, 0, 0);
        __syncthreads();
    }

#pragma unroll
    for (int i = 0; i < 4; i++) {
        int gm0 = row0 + wm * 64 + i * 16 + quad * 4;
#pragma unroll
        for (int r = 0; r < 4; r++) {
            int gm = gm0 + r;
            if (gm < mvalid) {
#pragma unroll
                for (int j = 0; j < 4; j++) {
                    int col = col0 + wn * 64 + l16 + j * 16;
                    if (col < ncols) {
                        float v = acc[i][j][r];
                        if (bias) v += bias[col];
                        if (RELU) v = fmaxf(v, 0.f);
                        if (OUT_BF16) Cb[(size_t)gm * ldc + col] = __float2bfloat16(v);
                        else          Cf[(size_t)gm * ldc + col] = v;
                    }
                }
            }
        }
    }
}

// V = Abf(2048x256) @ Bt^T(32768x256) -> bf16 (specialized: huge N stride)
__global__ __launch_bounds__(256) void k_gemm_V_mfma(const __hip_bfloat16* __restrict__ A,
                                                     const __hip_bfloat16* __restrict__ Bt,
                                                     __hip_bfloat16* __restrict__ C) {
    __shared__ short As[128 * 32];
    __shared__ short Bs[128 * 32];
    int t = threadIdx.x;
    int lane = t & 63, wave = t >> 6;
    int wm = wave >> 1, wn = wave & 1;
    int quad = lane >> 4, l16 = lane & 15;
    int row0 = blockIdx.y * 128, col0 = blockIdx.x * 128;

    f32x4 acc[4][4] = {};
    int r_ld = (lane >> 2);
    int koff = (lane & 3) * 8;

    for (int k0 = 0; k0 < H_; k0 += 32) {
#pragma unroll
        for (int c = 0; c < 4; c++) {
            int q = wave * 4 + c;
            int ch = q & 7;
            int r = ch * 16 + r_ld;
            const __hip_bfloat16* gp;
            short* lp;
            if (q < 8) { gp = A  + ((size_t)(row0 + r) << 8) + k0 + koff; lp = As + ch * 512; }
            else       { gp = Bt + ((size_t)(col0 + r) << 8) + k0 + koff; lp = Bs + ch * 512; }
            __builtin_amdgcn_global_load_lds(
                (const __attribute__((address_space(1))) unsigned int*)(uintptr_t)gp,
                (__attribute__((address_space(3))) unsigned int*)(uintptr_t)lp,
                16, 0, 0);
        }
        __syncthreads();
        bf16x8 a[4], b[4];
#pragma unroll
        for (int i = 0; i < 4; i++)
            a[i] = *(const bf16x8*)&As[(wm * 64 + i * 16 + l16) * 32 + quad * 8];
#pragma unroll
        for (int j = 0; j < 4; j++)
            b[j] = *(const bf16x8*)&Bs[(wn * 64 + j * 16 + l16) * 32 + quad * 8];
#pragma unroll
        for (int i = 0; i < 4; i++)
#pragma unroll
            for (int j = 0; j < 4; j++)
                acc[i][j] = __builtin_amdgcn_mfma_f32_16x16x32_bf16(a[i], b[j], acc[i][j], 0, 0, 0);
        __syncthreads();
    }

#pragma unroll
    for (int i = 0; i < 4; i++) {
        int gm0 = row0 + wm * 64 + i * 16 + quad * 4;
#pragma unroll
        for (int r = 0; r < 4; r++) {
            int gm = gm0 + r;
            if (gm < N_) {
                size_t base = (size_t)gm * NV_ + col0 + wn * 64 + l16;
#pragma unroll
                for (int j = 0; j < 4; j++)
                    C[base + j * 16] = __float2bfloat16(acc[i][j][r]);
            }
        }
    }
}

// GRU gates GEMM: z=0 -> gi = Mbf @ WihB^T + bih; z=1 -> gh = Abf @ WhhB^T + bhh.
__global__ __launch_bounds__(256) void k_gemm_gru_mfma(const __hip_bfloat16* __restrict__ A0,
                                                       const __hip_bfloat16* __restrict__ A1,
                                                       const __hip_bfloat16* __restrict__ W0,
                                                       const __hip_bfloat16* __restrict__ W1,
                                                       const float* __restrict__ b0,
                                                       const float* __restrict__ b1,
                                                       float* __restrict__ C0,
                                                       float* __restrict__ C1) {
    __shared__ short As[128 * 32];
    __shared__ short Bs[128 * 32];
    int t = threadIdx.x;
    int lane = t & 63, wave = t >> 6;
    int wm = wave >> 1, wn = wave & 1;
    int quad = lane >> 4, l16 = lane & 15;
    int row0 = blockIdx.y * 128, col0 = blockIdx.x * 128;
    const __hip_bfloat16* A  = blockIdx.z ? A1 : A0;
    const __hip_bfloat16* Bt = blockIdx.z ? W1 : W0;
    const float* bias        = blockIdx.z ? b1 : b0;
    float* C                 = blockIdx.z ? C1 : C0;

    f32x4 acc[4][4] = {};
    int r_ld = (lane >> 2);
    int koff = (lane & 3) * 8;

    for (int k0 = 0; k0 < H_; k0 += 32) {
#pragma unroll
        for (int c = 0; c < 4; c++) {
            int q = wave * 4 + c;
            int ch = q & 7;
            int r = ch * 16 + r_ld;
            const __hip_bfloat16* gp;
            short* lp;
            if (q < 8) { gp = A  + ((size_t)(row0 + r) << 8) + k0 + koff; lp = As + ch * 512; }
            else       { gp = Bt + ((size_t)(col0 + r) << 8) + k0 + koff; lp = Bs + ch * 512; }
            __builtin_amdgcn_global_load_lds(
                (const __attribute__((address_space(1))) unsigned int*)(uintptr_t)gp,
                (__attribute__((address_space(3))) unsigned int*)(uintptr_t)lp,
                16, 0, 0);
        }
        __syncthreads();
        bf16x8 a[4], b[4];
#pragma unroll
        for (int i = 0; i < 4; i++)
            a[i] = *(const bf16x8*)&As[(wm * 64 + i * 16 + l16) * 32 + quad * 8];
#pragma unroll
        for (int j = 0; j < 4; j++)
            b[j] = *(const bf16x8*)&Bs[(wn * 64 + j * 16 + l16) * 32 + quad * 8];
#pragma unroll
        for (int i = 0; i < 4; i++)
#pragma unroll
            for (int j = 0; j < 4; j++)
                acc[i][j] = __builtin_amdgcn_mfma_f32_16x16x32_bf16(a[i], b[j], acc[i][j], 0, 0, 0);
        __syncthreads();
    }

#pragma unroll
    for (int i = 0; i < 4; i++) {
        int gm0 = row0 + wm * 64 + i * 16 + quad * 4;
#pragma unroll
        for (int r = 0; r < 4; r++) {
            int gm = gm0 + r;
            if (gm < N_) {
                int col = col0 + wn * 64 + l16;
                size_t base = (size_t)gm * NG_ + col;
#pragma unroll
                for (int j = 0; j < 4; j++)
                    C[base + j * 16] = acc[i][j][r] + bias[col + j * 16];
            }
        }
    }
}

// msg[e,o] = he[e,:].V[row[e],o,:] + outb[row[e],o]; atomicAdd into agg[col[e],o]
__global__ void k_msg(const int* __restrict__ ei, const float* __restrict__ he,
                      const __hip_bfloat16* __restrict__ V, const float* __restrict__ outb,
                      float* __restrict__ agg) {
    int e = blockIdx.x, o = threadIdx.x;
    __shared__ float hs[KH_];
    if (o < KH_) hs[o] = he[e * KH_ + o];
    __syncthreads();
    int r = ei[e], c = ei[E_ + e];
    float acc = outb[(size_t)r * H_ + o];
    const uint4* vp4 = reinterpret_cast<const uint4*>(V + (size_t)r * NV_ + (size_t)o * KH_);
#pragma unroll
    for (int q = 0; q < KH_ / 8; q++) {
        uint4 u = vp4[q];
        const float* hp = hs + q * 8;
        acc += hp[0] * bf_lo(u.x) + hp[1] * bf_hi(u.x)
             + hp[2] * bf_lo(u.y) + hp[3] * bf_hi(u.y)
             + hp[4] * bf_lo(u.z) + hp[5] * bf_hi(u.z)
             + hp[6] * bf_lo(u.w) + hp[7] * bf_hi(u.w);
    }
    atomicAdd(&agg[(size_t)c * H_ + o], acc);
}

// Mbf = bf16(relu(agg / max(counts,1) + conv_b))
__global__ void k_m(const float* __restrict__ agg, const float* __restrict__ counts,
                    const float* __restrict__ conv_b, __hip_bfloat16* __restrict__ Mbf) {
    int i = blockIdx.x * blockDim.x + threadIdx.x;
    if (i >= N_ * H_) return;
    int n = i >> 8, o = i & 255;
    float c = fmaxf(counts[n], 1.0f);
    Mbf[i] = __float2bfloat16(fmaxf(agg[i] / c + conv_b[o], 0.f));
}

__global__ void k_gru_update(const float* __restrict__ gi, const float* __restrict__ gh,
                             float* __restrict__ h) {
    int i = blockIdx.x * blockDim.x + threadIdx.x;
    if (i >= N_ * H_) return;
    int n = i >> 8, j = i & 255;
    const float* gip = gi + (size_t)n * NG_;
    const float* ghp = gh + (size_t)n * NG_;
    float r = 1.f / (1.f + expf(-(gip[j] + ghp[j])));
    float z = 1.f / (1.f + expf(-(gip[H_ + j] + ghp[H_ + j])));
    float nn = tanhf(gip[2 * H_ + j] + r * ghp[2 * H_ + j]);
    h[i] = (1.f - z) * nn + z * h[i];
}

// batchnorm stats over E rows, per column j   grid 128, block 256
__global__ void k_bnstats(const float* __restrict__ h1, float* __restrict__ mu,
                          float* __restrict__ rsig) {
    int j = blockIdx.x, t = threadIdx.x;
    float s = 0.f, ss = 0.f;
    for (int e = t; e < E_; e += 256) {
        float v = h1[(size_t)e * 128 + j];
        s += v;
        ss += v * v;
    }
    __shared__ float rs[256], rss[256];
    rs[t] = s; rss[t] = ss;
    __syncthreads();
    for (int off = 128; off > 0; off >>= 1) {
        if (t < off) { rs[t] += rs[t + off]; rss[t] += rss[t + off]; }
        __syncthreads();
    }
    if (t == 0) {
        float m_ = rs[0] / E_;
        float v_ = rss[0] / E_ - m_ * m_;
        mu[j] = m_;
        rsig[j] = rsqrtf(v_ + 1e-5f);
    }
}

// precs[e] = relu(bn(h1[e])) . l6_W2 + b
__global__ void k_precs(const float* __restrict__ h1, const float* __restrict__ mu,
                        const float* __restrict__ rsig, const float* __restrict__ g,
                        const float* __restrict__ bb, const float* __restrict__ W2,
                        const float* __restrict__ b2, float* __restrict__ out) {
    int e = blockIdx.x * blockDim.x + threadIdx.x;
    if (e >= E_) return;
    float acc = b2[0];
#pragma unroll 4
    for (int j = 0; j < 128; j++) {
        float v = (h1[(size_t)e * 128 + j] - mu[j]) * rsig[j] * g[j] + bb[j];
        acc += fmaxf(v, 0.f) * W2[j];
    }
    out[(size_t)E_ * 242 + e] = acc;
}

extern "C" void kernel_launch(void* const* d_in, const int* in_sizes, int n_in,
                              void* d_out, int out_size, void* d_ws, size_t ws_size,
                              hipStream_t stream) {
    const int*   x        = (const int*)  d_in[0];
    const float* pos      = (const float*)d_in[1];
    const int*   ei       = (const int*)  d_in[2];
    const float* edge_atr = (const float*)d_in[3];
    const float* emb      = (const float*)d_in[4];
    const float* lin0_W   = (const float*)d_in[5];
    const float* lin0_b   = (const float*)d_in[6];
    const float* mlp1_W   = (const float*)d_in[7];
    const float* mlp1_b   = (const float*)d_in[8];
    const float* mlp2_W   = (const float*)d_in[9];
    const float* mlp2_b   = (const float*)d_in[10];
    const float* conv_b   = (const float*)d_in[11];
    const float* gru_Wih  = (const float*)d_in[12];
    const float* gru_Whh  = (const float*)d_in[13];
    const float* gru_bih  = (const float*)d_in[14];
    const float* gru_bhh  = (const float*)d_in[15];
    const float* lin1_W   = (const float*)d_in[16];
    const float* lin1_b   = (const float*)d_in[17];
    const float* lin2_W   = (const float*)d_in[18];
    const float* lin2_b   = (const float*)d_in[19];
    const float* l6_W1    = (const float*)d_in[20];
    const float* l6_b1    = (const float*)d_in[21];
    const float* bn_g     = (const float*)d_in[22];
    const float* bn_b     = (const float*)d_in[23];
    const float* l6_W2    = (const float*)d_in[24];
    const float* l6_b2    = (const float*)d_in[25];
    float* out = (float*)d_out;

    // workspace layout
    char* w = (char*)d_ws;
    size_t off = 0;
    auto alloc = [&](size_t bytes) -> void* {
        void* p = w + off;
        off = (off + bytes + 255) & ~(size_t)255;
        return p;
    };
    float* hbuf   = (float*)alloc((size_t)N_ * H_ * 4);
    float* aggm   = (float*)alloc((size_t)N_ * H_ * 4);
    float* outb   = (float*)alloc((size_t)N_ * H_ * 4);
    float* he     = (float*)alloc((size_t)E_ * KH_ * 4);
    float* gi     = (float*)alloc((size_t)N_ * NG_ * 4);
    float* gh     = (float*)alloc((size_t)N_ * NG_ * 4);
    float* h1     = (float*)alloc((size_t)E_ * 128 * 4);
    float* counts = (float*)alloc((size_t)N_ * 4);
    float* mu     = (float*)alloc(128 * 4);
    float* rsig   = (float*)alloc(128 * 4);
    __hip_bfloat16* V      = (__hip_bfloat16*)alloc((size_t)N_ * NV_ * 2);     // 131 MB
    __hip_bfloat16* Abf    = (__hip_bfloat16*)alloc((size_t)MPAD_ * H_ * 2);
    __hip_bfloat16* Mbf    = (__hip_bfloat16*)alloc((size_t)MPAD_ * H_ * 2);
    __hip_bfloat16* Bt     = (__hip_bfloat16*)alloc((size_t)NV_ * H_ * 2);     // 16.8 MB
    __hip_bfloat16* WihB   = (__hip_bfloat16*)alloc((size_t)NG_ * H_ * 2);
    __hip_bfloat16* WhhB   = (__hip_bfloat16*)alloc((size_t)NG_ * H_ * 2);
    __hip_bfloat16* lin1Wb = (__hip_bfloat16*)alloc((size_t)H_ * 2 * H_ * 2);
    __hip_bfloat16* l6W1b  = (__hip_bfloat16*)alloc((size_t)128 * 2 * H_ * 2);
    __hip_bfloat16* lin2Wb = (__hip_bfloat16*)alloc((size_t)H_ * H_ * 2);      // padded 256x256
    __hip_bfloat16* BtB    = (__hip_bfloat16*)alloc((size_t)H_ * H_ * 2);      // mlp2_b transposed
    __hip_bfloat16* Cbf    = (__hip_bfloat16*)alloc((size_t)E_ * 2 * H_ * 2);  // concat, 4 MB
    __hip_bfloat16* o1bf   = (__hip_bfloat16*)alloc((size_t)E_ * H_ * 2);

    k_lin0<<<N_, 256, 0, stream>>>(x, pos, emb, lin0_W, lin0_b, hbuf);
    k_he<<<E_, 128, 0, stream>>>(edge_atr, mlp1_W, mlp1_b, he);
    hipMemsetAsync(counts, 0, (size_t)N_ * 4, stream);
    k_counts<<<(E_ + 255) / 256, 256, 0, stream>>>(ei, counts);
    k_trans_bt<<<dim3(NV_ / 64, H_ / 32), 256, 0, stream>>>(mlp2_W, Bt);
    k_prep_w<<<768, 256, 0, stream>>>(gru_Wih, gru_Whh, lin1_W, l6_W1, lin2_W, mlp2_b,
                                      WihB, WhhB, lin1Wb, l6W1b, lin2Wb, BtB);

    for (int it = 0; it < 3; it++) {
        k_abf<<<MPAD_, 256, 0, stream>>>(hbuf, Abf);
        // outb = Abf @ BtB^T (fp32, no bias)
        k_gemm_nt<256, false, false><<<dim3(2, MPAD_ / 128), 256, 0, stream>>>(
            Abf, BtB, outb, nullptr, nullptr, H_, H_, N_);
        dim3 gv(NV_ / 128, MPAD_ / 128);
        k_gemm_V_mfma<<<gv, 256, 0, stream>>>(Abf, Bt, V);
        hipMemsetAsync(aggm, 0, (size_t)N_ * H_ * 4, stream);
        k_msg<<<E_, 256, 0, stream>>>(ei, he, V, outb, aggm);
        k_m<<<(N_ * H_ + 255) / 256, 256, 0, stream>>>(aggm, counts, conv_b, Mbf);
        dim3 gg(NG_ / 128, MPAD_ / 128, 2);
        k_gemm_gru_mfma<<<gg, 256, 0, stream>>>(Mbf, Abf, WihB, WhhB,
                                                gru_bih, gru_bhh, gi, gh);
        k_gru_update<<<(N_ * H_ + 255) / 256, 256, 0, stream>>>(gi, gh, hbuf);
    }

    k_concat<<<E_, 256, 0, stream>>>(ei, hbuf, Cbf);
    // o1 = relu(Cbf @ lin1Wb^T + lin1_b) -> bf16
    k_gemm_nt<512, true, true><<<dim3(2, E_ / 128), 256, 0, stream>>>(
        Cbf, lin1Wb, nullptr, o1bf, lin1_b, H_, H_, E_);
    // out2 = o1bf @ lin2Wb^T + lin2_b (242 cols) -> d_out
    k_gemm_nt<256, false, false><<<dim3(2, E_ / 128), 256, 0, stream>>>(
        o1bf, lin2Wb, out, nullptr, lin2_b, 242, 242, E_);
    // h1 = Cbf @ l6W1b^T + l6_b1 (128 cols, fp32)
    k_gemm_nt<512, false, false><<<dim3(1, E_ / 128), 256, 0, stream>>>(
        Cbf, l6W1b, h1, nullptr, l6_b1, 128, 128, E_);
    k_bnstats<<<128, 256, 0, stream>>>(h1, mu, rsig);
    k_precs<<<(E_ + 255) / 256, 256, 0, stream>>>(h1, mu, rsig, bn_g, bn_b, l6_W2, l6_b2, out);
}

// Round 5
// 554.876 us; speedup vs baseline: 6.0657x; 1.1511x over previous
//
#include <hip/hip_runtime.h>
#include <hip/hip_bf16.h>

// Problem constants (fixed by the reference)
constexpr int N_ = 2000;   // nodes
constexpr int E_ = 4096;   // edges
constexpr int H_ = 256;    // hidden
constexpr int KH_ = 128;   // he dim (mlp1 out)
constexpr int NV_ = H_ * KH_; // 32768, V row length (layout [o*128+k]) — fp8 bytes
constexpr int MPAD_ = 2048;   // padded M for node-side MFMA GEMMs
constexpr int NG_ = 768;      // GRU gate width (3*H)
constexpr float VSCALE = 64.f;     // fp8 scale for V (avoids e4m3 subnormals)
constexpr float VSCALE_INV = 1.f / 64.f;

typedef short bf16x8 __attribute__((ext_vector_type(8)));
typedef float f32x4  __attribute__((ext_vector_type(4)));
typedef float f32x2  __attribute__((ext_vector_type(2)));

__device__ __forceinline__ float bf_lo(unsigned u) { return __uint_as_float(u << 16); }
__device__ __forceinline__ float bf_hi(unsigned u) { return __uint_as_float(u & 0xffff0000u); }

// out = relu([emb[x], pos] @ lin0_W.T + b); also emits Abf (bf16, zero-padded rows).
// grid MPAD_, block 256
__global__ void k_lin0(const int* __restrict__ x, const float* __restrict__ pos,
                       const float* __restrict__ emb, const float* __restrict__ W,
                       const float* __restrict__ b, float* __restrict__ out,
                       __hip_bfloat16* __restrict__ Abf) {
    int n = blockIdx.x, t = threadIdx.x;
    if (n >= N_) { Abf[(size_t)n * H_ + t] = __float2bfloat16(0.f); return; }
    __shared__ float in_p[8];
    if (t < 5) in_p[t] = emb[x[n] * 5 + t];
    else if (t < 8) in_p[t] = pos[n * 3 + (t - 5)];
    __syncthreads();
    float acc = b[t];
#pragma unroll
    for (int i = 0; i < 8; i++) acc += in_p[i] * W[t * 8 + i];
    float v = fmaxf(acc, 0.f);
    out[n * H_ + t] = v;
    Abf[(size_t)n * H_ + t] = __float2bfloat16(v);
}

// he = relu(edge_atr @ mlp1_W.T + b)   grid E, block 128
__global__ void k_he(const float* __restrict__ ea, const float* __restrict__ W,
                     const float* __restrict__ b, float* __restrict__ he) {
    int e = blockIdx.x, t = threadIdx.x;
    __shared__ float a[5];
    if (t < 5) a[t] = ea[e * 5 + t];
    __syncthreads();
    float acc = b[t];
#pragma unroll
    for (int i = 0; i < 5; i++) acc += a[i] * W[t * 5 + i];
    he[e * KH_ + t] = fmaxf(acc, 0.f);
}

__global__ void k_counts(const int* __restrict__ ei, float* __restrict__ counts) {
    int e = blockIdx.x * blockDim.x + threadIdx.x;
    if (e < E_) atomicAdd(&counts[ei[E_ + e]], 1.0f);
}

// Bt[n][k] = mlp2_W[k*32768 + n] as bf16 (transpose+convert), once per launch.
__global__ void k_trans_bt(const float* __restrict__ W, __hip_bfloat16* __restrict__ Bt) {
    __shared__ float tile[32][65];
    int t = threadIdx.x;
    int n0 = blockIdx.x * 64, k0 = blockIdx.y * 32;
#pragma unroll
    for (int i = 0; i < 8; i++) {
        int idx = t + i * 256;
        int kk = idx >> 6, nn = idx & 63;
        tile[kk][nn] = W[(size_t)(k0 + kk) * NV_ + n0 + nn];
    }
    __syncthreads();
#pragma unroll
    for (int i = 0; i < 8; i++) {
        int idx = t + i * 256;
        int nn = idx >> 5, kk = idx & 31;
        Bt[(size_t)(n0 + nn) * H_ + k0 + kk] = __float2bfloat16(tile[kk][nn]);
    }
}

// One-time weight preps (bf16 converts + lin2 pad + mlp2_b transpose).  grid 768, block 256
__global__ void k_prep_w(const float* __restrict__ Wih, const float* __restrict__ Whh,
                         const float* __restrict__ lin1W, const float* __restrict__ l6W1,
                         const float* __restrict__ lin2W, const float* __restrict__ b2,
                         __hip_bfloat16* __restrict__ WihB, __hip_bfloat16* __restrict__ WhhB,
                         __hip_bfloat16* __restrict__ lin1Wb, __hip_bfloat16* __restrict__ l6W1b,
                         __hip_bfloat16* __restrict__ lin2Wb, __hip_bfloat16* __restrict__ BtB) {
    int i = blockIdx.x * 256 + threadIdx.x;
    if (i < NG_ * H_) {
        WihB[i] = __float2bfloat16(Wih[i]);
        WhhB[i] = __float2bfloat16(Whh[i]);
    }
    if (i < H_ * 2 * H_) {
        lin1Wb[i] = __float2bfloat16(lin1W[i]);
    }
    if (i < 128 * 2 * H_) {
        l6W1b[i] = __float2bfloat16(l6W1[i]);
        int r = i >> 8, k = i & 255;
        lin2Wb[i] = __float2bfloat16(r < 242 ? lin2W[r * H_ + k] : 0.f);
        int o = i >> 8, h = i & 255;
        BtB[o * H_ + h] = __float2bfloat16(b2[h * H_ + o]);
    }
}

// Cbf[e] = bf16([h[row[e]], h[col[e]]])   grid E, block 256
__global__ void k_concat(const int* __restrict__ ei, const float* __restrict__ h,
                         __hip_bfloat16* __restrict__ Cbf) {
    int e = blockIdx.x, t = threadIdx.x;
    int r = ei[e], c = ei[E_ + e];
    Cbf[(size_t)e * 512 + t]       = __float2bfloat16(h[(size_t)r * H_ + t]);
    Cbf[(size_t)e * 512 + 256 + t] = __float2bfloat16(h[(size_t)c * H_ + t]);
}

// Generic MFMA GEMM: C(MxN) = A(MxKD bf16) @ Bt(NxKD bf16)^T [+bias][relu].
template <int KD, bool RELU, bool OUT_BF16>
__global__ __launch_bounds__(256) void k_gemm_nt(const __hip_bfloat16* __restrict__ A,
                                                 const __hip_bfloat16* __restrict__ Bt,
                                                 float* __restrict__ Cf,
                                                 __hip_bfloat16* __restrict__ Cb,
                                                 const float* __restrict__ bias,
                                                 int ldc, int ncols, int mvalid) {
    __shared__ short As[128 * 32];
    __shared__ short Bs[128 * 32];
    int t = threadIdx.x;
    int lane = t & 63, wave = t >> 6;
    int wm = wave >> 1, wn = wave & 1;
    int quad = lane >> 4, l16 = lane & 15;
    int row0 = blockIdx.y * 128, col0 = blockIdx.x * 128;

    f32x4 acc[4][4] = {};
    int r_ld = (lane >> 2);
    int koff = (lane & 3) * 8;

    for (int k0 = 0; k0 < KD; k0 += 32) {
#pragma unroll
        for (int c = 0; c < 4; c++) {
            int q = wave * 4 + c;
            int ch = q & 7;
            int r = ch * 16 + r_ld;
            const __hip_bfloat16* gp;
            short* lp;
            if (q < 8) { gp = A  + (size_t)(row0 + r) * KD + k0 + koff; lp = As + ch * 512; }
            else       { gp = Bt + (size_t)(col0 + r) * KD + k0 + koff; lp = Bs + ch * 512; }
            __builtin_amdgcn_global_load_lds(
                (const __attribute__((address_space(1))) unsigned int*)(uintptr_t)gp,
                (__attribute__((address_space(3))) unsigned int*)(uintptr_t)lp,
                16, 0, 0);
        }
        __syncthreads();
        bf16x8 a[4], b[4];
#pragma unroll
        for (int i = 0; i < 4; i++)
            a[i] = *(const bf16x8*)&As[(wm * 64 + i * 16 + l16) * 32 + quad * 8];
#pragma unroll
        for (int j = 0; j < 4; j++)
            b[j] = *(const bf16x8*)&Bs[(wn * 64 + j * 16 + l16) * 32 + quad * 8];
#pragma unroll
        for (int i = 0; i < 4; i++)
#pragma unroll
            for (int j = 0; j < 4; j++)
                acc[i][j] = __builtin_amdgcn_mfma_f32_16x16x32_bf16(a[i], b[j], acc[i][j], 0, 0, 0);
        __syncthreads();
    }

#pragma unroll
    for (int i = 0; i < 4; i++) {
        int gm0 = row0 + wm * 64 + i * 16 + quad * 4;
#pragma unroll
        for (int r = 0; r < 4; r++) {
            int gm = gm0 + r;
            if (gm < mvalid) {
#pragma unroll
                for (int j = 0; j < 4; j++) {
                    int col = col0 + wn * 64 + l16 + j * 16;
                    if (col < ncols) {
                        float v = acc[i][j][r];
                        if (bias) v += bias[col];
                        if (RELU) v = fmaxf(v, 0.f);
                        if (OUT_BF16) Cb[(size_t)gm * ldc + col] = __float2bfloat16(v);
                        else          Cf[(size_t)gm * ldc + col] = v;
                    }
                }
            }
        }
    }
}

// V = Abf(2048x256) @ Bt^T(32768x256) -> fp8 e4m3 (x64 scale), coalesced epilogue.
__global__ __launch_bounds__(256) void k_gemm_V_mfma(const __hip_bfloat16* __restrict__ A,
                                                     const __hip_bfloat16* __restrict__ Bt,
                                                     unsigned char* __restrict__ V8) {
    __shared__ short As[128 * 32];
    __shared__ short Bs[128 * 32];
    __shared__ short Ps[128 * 136];   // epilogue repack (pad 8 shorts: bank-rotating, 16B-aligned rows)
    int t = threadIdx.x;
    int lane = t & 63, wave = t >> 6;
    int wm = wave >> 1, wn = wave & 1;
    int quad = lane >> 4, l16 = lane & 15;
    int row0 = blockIdx.y * 128, col0 = blockIdx.x * 128;

    f32x4 acc[4][4] = {};
    int r_ld = (lane >> 2);
    int koff = (lane & 3) * 8;

    for (int k0 = 0; k0 < H_; k0 += 32) {
#pragma unroll
        for (int c = 0; c < 4; c++) {
            int q = wave * 4 + c;
            int ch = q & 7;
            int r = ch * 16 + r_ld;
            const __hip_bfloat16* gp;
            short* lp;
            if (q < 8) { gp = A  + ((size_t)(row0 + r) << 8) + k0 + koff; lp = As + ch * 512; }
            else       { gp = Bt + ((size_t)(col0 + r) << 8) + k0 + koff; lp = Bs + ch * 512; }
            __builtin_amdgcn_global_load_lds(
                (const __attribute__((address_space(1))) unsigned int*)(uintptr_t)gp,
                (__attribute__((address_space(3))) unsigned int*)(uintptr_t)lp,
                16, 0, 0);
        }
        __syncthreads();
        bf16x8 a[4], b[4];
#pragma unroll
        for (int i = 0; i < 4; i++)
            a[i] = *(const bf16x8*)&As[(wm * 64 + i * 16 + l16) * 32 + quad * 8];
#pragma unroll
        for (int j = 0; j < 4; j++)
            b[j] = *(const bf16x8*)&Bs[(wn * 64 + j * 16 + l16) * 32 + quad * 8];
#pragma unroll
        for (int i = 0; i < 4; i++)
#pragma unroll
            for (int j = 0; j < 4; j++)
                acc[i][j] = __builtin_amdgcn_mfma_f32_16x16x32_bf16(a[i], b[j], acc[i][j], 0, 0, 0);
        __syncthreads();
    }

    // stage scaled bf16 tile into LDS
#pragma unroll
    for (int i = 0; i < 4; i++) {
        int rowb = wm * 64 + i * 16 + quad * 4;
#pragma unroll
        for (int r = 0; r < 4; r++) {
#pragma unroll
            for (int j = 0; j < 4; j++) {
                int col = wn * 64 + j * 16 + l16;
                __hip_bfloat16 bv = __float2bfloat16(acc[i][j][r] * VSCALE);
                Ps[(rowb + r) * 136 + col] = *(short*)&bv;
            }
        }
    }
    __syncthreads();
    // coalesced fp8 copy-out: 16384 elems, 8/thread/pass, 8 passes
#pragma unroll
    for (int p = 0; p < 8; p++) {
        int e = (p * 256 + t) * 8;
        int row = e >> 7, col = e & 127;
        int gm = row0 + row;
        if (gm < N_) {
            uint4 u = *(const uint4*)&Ps[row * 136 + col];
            float f0 = bf_lo(u.x), f1 = bf_hi(u.x), f2 = bf_lo(u.y), f3 = bf_hi(u.y);
            float f4 = bf_lo(u.z), f5 = bf_hi(u.z), f6 = bf_lo(u.w), f7 = bf_hi(u.w);
            unsigned px = __builtin_amdgcn_cvt_pk_fp8_f32(f0, f1, 0, false);
            px = __builtin_amdgcn_cvt_pk_fp8_f32(f2, f3, px, true);
            unsigned py = __builtin_amdgcn_cvt_pk_fp8_f32(f4, f5, 0, false);
            py = __builtin_amdgcn_cvt_pk_fp8_f32(f6, f7, py, true);
            uint2 o2; o2.x = px; o2.y = py;
            *(uint2*)(V8 + (size_t)gm * NV_ + col0 + col) = o2;
        }
    }
}

// GRU gates GEMM: z=0 -> gi = Mbf @ WihB^T + bih; z=1 -> gh = Abf @ WhhB^T + bhh.
__global__ __launch_bounds__(256) void k_gemm_gru_mfma(const __hip_bfloat16* __restrict__ A0,
                                                       const __hip_bfloat16* __restrict__ A1,
                                                       const __hip_bfloat16* __restrict__ W0,
                                                       const __hip_bfloat16* __restrict__ W1,
                                                       const float* __restrict__ b0,
                                                       const float* __restrict__ b1,
                                                       float* __restrict__ C0,
                                                       float* __restrict__ C1) {
    __shared__ short As[128 * 32];
    __shared__ short Bs[128 * 32];
    int t = threadIdx.x;
    int lane = t & 63, wave = t >> 6;
    int wm = wave >> 1, wn = wave & 1;
    int quad = lane >> 4, l16 = lane & 15;
    int row0 = blockIdx.y * 128, col0 = blockIdx.x * 128;
    const __hip_bfloat16* A  = blockIdx.z ? A1 : A0;
    const __hip_bfloat16* Bt = blockIdx.z ? W1 : W0;
    const float* bias        = blockIdx.z ? b1 : b0;
    float* C                 = blockIdx.z ? C1 : C0;

    f32x4 acc[4][4] = {};
    int r_ld = (lane >> 2);
    int koff = (lane & 3) * 8;

    for (int k0 = 0; k0 < H_; k0 += 32) {
#pragma unroll
        for (int c = 0; c < 4; c++) {
            int q = wave * 4 + c;
            int ch = q & 7;
            int r = ch * 16 + r_ld;
            const __hip_bfloat16* gp;
            short* lp;
            if (q < 8) { gp = A  + ((size_t)(row0 + r) << 8) + k0 + koff; lp = As + ch * 512; }
            else       { gp = Bt + ((size_t)(col0 + r) << 8) + k0 + koff; lp = Bs + ch * 512; }
            __builtin_amdgcn_global_load_lds(
                (const __attribute__((address_space(1))) unsigned int*)(uintptr_t)gp,
                (__attribute__((address_space(3))) unsigned int*)(uintptr_t)lp,
                16, 0, 0);
        }
        __syncthreads();
        bf16x8 a[4], b[4];
#pragma unroll
        for (int i = 0; i < 4; i++)
            a[i] = *(const bf16x8*)&As[(wm * 64 + i * 16 + l16) * 32 + quad * 8];
#pragma unroll
        for (int j = 0; j < 4; j++)
            b[j] = *(const bf16x8*)&Bs[(wn * 64 + j * 16 + l16) * 32 + quad * 8];
#pragma unroll
        for (int i = 0; i < 4; i++)
#pragma unroll
            for (int j = 0; j < 4; j++)
                acc[i][j] = __builtin_amdgcn_mfma_f32_16x16x32_bf16(a[i], b[j], acc[i][j], 0, 0, 0);
        __syncthreads();
    }

#pragma unroll
    for (int i = 0; i < 4; i++) {
        int gm0 = row0 + wm * 64 + i * 16 + quad * 4;
#pragma unroll
        for (int r = 0; r < 4; r++) {
            int gm = gm0 + r;
            if (gm < N_) {
                int col = col0 + wn * 64 + l16;
                size_t base = (size_t)gm * NG_ + col;
#pragma unroll
                for (int j = 0; j < 4; j++)
                    C[base + j * 16] = acc[i][j][r] + bias[col + j * 16];
            }
        }
    }
}

// msg[e,o] = (he[e,:]/64).(fp8 V[row[e],o,:]) + outb[row[e],o]; atomicAdd into agg[col[e],o]
__global__ void k_msg(const int* __restrict__ ei, const float* __restrict__ he,
                      const unsigned char* __restrict__ V8, const float* __restrict__ outb,
                      float* __restrict__ agg) {
    int e = blockIdx.x, o = threadIdx.x;
    __shared__ float hs[KH_];
    if (o < KH_) hs[o] = he[e * KH_ + o] * VSCALE_INV;
    __syncthreads();
    int r = ei[e], c = ei[E_ + e];
    float acc = outb[(size_t)r * H_ + o];
    const uint4* vp = reinterpret_cast<const uint4*>(V8 + (size_t)r * NV_ + (size_t)o * KH_);
#pragma unroll
    for (int q = 0; q < 8; q++) {       // 8 x uint4 = 128 fp8
        uint4 u = vp[q];
        const float* hp = hs + q * 16;
        f32x2 f;
        f = __builtin_amdgcn_cvt_pk_f32_fp8(u.x, false); acc += hp[0]  * f.x + hp[1]  * f.y;
        f = __builtin_amdgcn_cvt_pk_f32_fp8(u.x, true);  acc += hp[2]  * f.x + hp[3]  * f.y;
        f = __builtin_amdgcn_cvt_pk_f32_fp8(u.y, false); acc += hp[4]  * f.x + hp[5]  * f.y;
        f = __builtin_amdgcn_cvt_pk_f32_fp8(u.y, true);  acc += hp[6]  * f.x + hp[7]  * f.y;
        f = __builtin_amdgcn_cvt_pk_f32_fp8(u.z, false); acc += hp[8]  * f.x + hp[9]  * f.y;
        f = __builtin_amdgcn_cvt_pk_f32_fp8(u.z, true);  acc += hp[10] * f.x + hp[11] * f.y;
        f = __builtin_amdgcn_cvt_pk_f32_fp8(u.w, false); acc += hp[12] * f.x + hp[13] * f.y;
        f = __builtin_amdgcn_cvt_pk_f32_fp8(u.w, true);  acc += hp[14] * f.x + hp[15] * f.y;
    }
    atomicAdd(&agg[(size_t)c * H_ + o], acc);
}

// Mbf = bf16(relu(agg / max(counts,1) + conv_b))
__global__ void k_m(const float* __restrict__ agg, const float* __restrict__ counts,
                    const float* __restrict__ conv_b, __hip_bfloat16* __restrict__ Mbf) {
    int i = blockIdx.x * blockDim.x + threadIdx.x;
    if (i >= N_ * H_) return;
    int n = i >> 8, o = i & 255;
    float c = fmaxf(counts[n], 1.0f);
    Mbf[i] = __float2bfloat16(fmaxf(agg[i] / c + conv_b[o], 0.f));
}

// GRU pointwise; also refreshes Abf = bf16(h)
__global__ void k_gru_update(const float* __restrict__ gi, const float* __restrict__ gh,
                             float* __restrict__ h, __hip_bfloat16* __restrict__ Abf) {
    int i = blockIdx.x * blockDim.x + threadIdx.x;
    if (i >= N_ * H_) return;
    int n = i >> 8, j = i & 255;
    const float* gip = gi + (size_t)n * NG_;
    const float* ghp = gh + (size_t)n * NG_;
    float r = 1.f / (1.f + expf(-(gip[j] + ghp[j])));
    float z = 1.f / (1.f + expf(-(gip[H_ + j] + ghp[H_ + j])));
    float nn = tanhf(gip[2 * H_ + j] + r * ghp[2 * H_ + j]);
    float hv = (1.f - z) * nn + z * h[i];
    h[i] = hv;
    Abf[i] = __float2bfloat16(hv);
}

// batchnorm stats over E rows, per column j   grid 128, block 256
__global__ void k_bnstats(const float* __restrict__ h1, float* __restrict__ mu,
                          float* __restrict__ rsig) {
    int j = blockIdx.x, t = threadIdx.x;
    float s = 0.f, ss = 0.f;
    for (int e = t; e < E_; e += 256) {
        float v = h1[(size_t)e * 128 + j];
        s += v;
        ss += v * v;
    }
    __shared__ float rs[256], rss[256];
    rs[t] = s; rss[t] = ss;
    __syncthreads();
    for (int off = 128; off > 0; off >>= 1) {
        if (t < off) { rs[t] += rs[t + off]; rss[t] += rss[t + off]; }
        __syncthreads();
    }
    if (t == 0) {
        float m_ = rs[0] / E_;
        float v_ = rss[0] / E_ - m_ * m_;
        mu[j] = m_;
        rsig[j] = rsqrtf(v_ + 1e-5f);
    }
}

// precs[e] = relu(bn(h1[e])) . l6_W2 + b
__global__ void k_precs(const float* __restrict__ h1, const float* __restrict__ mu,
                        const float* __restrict__ rsig, const float* __restrict__ g,
                        const float* __restrict__ bb, const float* __restrict__ W2,
                        const float* __restrict__ b2, float* __restrict__ out) {
    int e = blockIdx.x * blockDim.x + threadIdx.x;
    if (e >= E_) return;
    float acc = b2[0];
#pragma unroll 4
    for (int j = 0; j < 128; j++) {
        float v = (h1[(size_t)e * 128 + j] - mu[j]) * rsig[j] * g[j] + bb[j];
        acc += fmaxf(v, 0.f) * W2[j];
    }
    out[(size_t)E_ * 242 + e] = acc;
}

extern "C" void kernel_launch(void* const* d_in, const int* in_sizes, int n_in,
                              void* d_out, int out_size, void* d_ws, size_t ws_size,
                              hipStream_t stream) {
    const int*   x        = (const int*)  d_in[0];
    const float* pos      = (const float*)d_in[1];
    const int*   ei       = (const int*)  d_in[2];
    const float* edge_atr = (const float*)d_in[3];
    const float* emb      = (const float*)d_in[4];
    const float* lin0_W   = (const float*)d_in[5];
    const float* lin0_b   = (const float*)d_in[6];
    const float* mlp1_W   = (const float*)d_in[7];
    const float* mlp1_b   = (const float*)d_in[8];
    const float* mlp2_W   = (const float*)d_in[9];
    const float* mlp2_b   = (const float*)d_in[10];
    const float* conv_b   = (const float*)d_in[11];
    const float* gru_Wih  = (const float*)d_in[12];
    const float* gru_Whh  = (const float*)d_in[13];
    const float* gru_bih  = (const float*)d_in[14];
    const float* gru_bhh  = (const float*)d_in[15];
    const float* lin1_W   = (const float*)d_in[16];
    const float* lin1_b   = (const float*)d_in[17];
    const float* lin2_W   = (const float*)d_in[18];
    const float* lin2_b   = (const float*)d_in[19];
    const float* l6_W1    = (const float*)d_in[20];
    const float* l6_b1    = (const float*)d_in[21];
    const float* bn_g     = (const float*)d_in[22];
    const float* bn_b     = (const float*)d_in[23];
    const float* l6_W2    = (const float*)d_in[24];
    const float* l6_b2    = (const float*)d_in[25];
    float* out = (float*)d_out;

    // workspace layout
    char* w = (char*)d_ws;
    size_t off = 0;
    auto alloc = [&](size_t bytes) -> void* {
        void* p = w + off;
        off = (off + bytes + 255) & ~(size_t)255;
        return p;
    };
    float* hbuf   = (float*)alloc((size_t)N_ * H_ * 4);
    float* aggm   = (float*)alloc((size_t)N_ * H_ * 4);
    float* outb   = (float*)alloc((size_t)N_ * H_ * 4);
    float* he     = (float*)alloc((size_t)E_ * KH_ * 4);
    float* gi     = (float*)alloc((size_t)N_ * NG_ * 4);
    float* gh     = (float*)alloc((size_t)N_ * NG_ * 4);
    float* h1     = (float*)alloc((size_t)E_ * 128 * 4);
    float* counts = (float*)alloc((size_t)N_ * 4);
    float* mu     = (float*)alloc(128 * 4);
    float* rsig   = (float*)alloc(128 * 4);
    unsigned char* V8      = (unsigned char*)alloc((size_t)N_ * NV_);          // 65.5 MB fp8
    __hip_bfloat16* Abf    = (__hip_bfloat16*)alloc((size_t)MPAD_ * H_ * 2);
    __hip_bfloat16* Mbf    = (__hip_bfloat16*)alloc((size_t)MPAD_ * H_ * 2);
    __hip_bfloat16* Bt     = (__hip_bfloat16*)alloc((size_t)NV_ * H_ * 2);     // 16.8 MB
    __hip_bfloat16* WihB   = (__hip_bfloat16*)alloc((size_t)NG_ * H_ * 2);
    __hip_bfloat16* WhhB   = (__hip_bfloat16*)alloc((size_t)NG_ * H_ * 2);
    __hip_bfloat16* lin1Wb = (__hip_bfloat16*)alloc((size_t)H_ * 2 * H_ * 2);
    __hip_bfloat16* l6W1b  = (__hip_bfloat16*)alloc((size_t)128 * 2 * H_ * 2);
    __hip_bfloat16* lin2Wb = (__hip_bfloat16*)alloc((size_t)H_ * H_ * 2);
    __hip_bfloat16* BtB    = (__hip_bfloat16*)alloc((size_t)H_ * H_ * 2);
    __hip_bfloat16* Cbf    = (__hip_bfloat16*)alloc((size_t)E_ * 2 * H_ * 2);
    __hip_bfloat16* o1bf   = (__hip_bfloat16*)alloc((size_t)E_ * H_ * 2);

    k_lin0<<<MPAD_, 256, 0, stream>>>(x, pos, emb, lin0_W, lin0_b, hbuf, Abf);
    k_he<<<E_, 128, 0, stream>>>(edge_atr, mlp1_W, mlp1_b, he);
    hipMemsetAsync(counts, 0, (size_t)N_ * 4, stream);
    k_counts<<<(E_ + 255) / 256, 256, 0, stream>>>(ei, counts);
    k_trans_bt<<<dim3(NV_ / 64, H_ / 32), 256, 0, stream>>>(mlp2_W, Bt);
    k_prep_w<<<768, 256, 0, stream>>>(gru_Wih, gru_Whh, lin1_W, l6_W1, lin2_W, mlp2_b,
                                      WihB, WhhB, lin1Wb, l6W1b, lin2Wb, BtB);

    for (int it = 0; it < 3; it++) {
        // outb = Abf @ BtB^T (fp32, no bias)
        k_gemm_nt<256, false, false><<<dim3(2, MPAD_ / 128), 256, 0, stream>>>(
            Abf, BtB, outb, nullptr, nullptr, H_, H_, N_);
        dim3 gv(NV_ / 128, MPAD_ / 128);
        k_gemm_V_mfma<<<gv, 256, 0, stream>>>(Abf, Bt, V8);
        hipMemsetAsync(aggm, 0, (size_t)N_ * H_ * 4, stream);
        k_msg<<<E_, 256, 0, stream>>>(ei, he, V8, outb, aggm);
        k_m<<<(N_ * H_ + 255) / 256, 256, 0, stream>>>(aggm, counts, conv_b, Mbf);
        dim3 gg(NG_ / 128, MPAD_ / 128, 2);
        k_gemm_gru_mfma<<<gg, 256, 0, stream>>>(Mbf, Abf, WihB, WhhB,
                                                gru_bih, gru_bhh, gi, gh);
        k_gru_update<<<(N_ * H_ + 255) / 256, 256, 0, stream>>>(gi, gh, hbuf, Abf);
    }

    k_concat<<<E_, 256, 0, stream>>>(ei, hbuf, Cbf);
    k_gemm_nt<512, true, true><<<dim3(2, E_ / 128), 256, 0, stream>>>(
        Cbf, lin1Wb, nullptr, o1bf, lin1_b, H_, H_, E_);
    k_gemm_nt<256, false, false><<<dim3(2, E_ / 128), 256, 0, stream>>>(
        o1bf, lin2Wb, out, nullptr, lin2_b, 242, 242, E_);
    k_gemm_nt<512, false, false><<<dim3(1, E_ / 128), 256, 0, stream>>>(
        Cbf, l6W1b, h1, nullptr, l6_b1, 128, 128, E_);
    k_bnstats<<<128, 256, 0, stream>>>(h1, mu, rsig);
    k_precs<<<(E_ + 255) / 256, 256, 0, stream>>>(h1, mu, rsig, bn_g, bn_b, l6_W2, l6_b2, out);
}